// Round 11
// baseline (486.534 us; speedup 1.0000x reference)
//
#include <hip/hip_runtime.h>
#include <hip/hip_bf16.h>

#define BB 16
#define TT 512
#define DD 64
#define HH 128
#define SS 100
#define MSZ 20
#define NROW (BB*TT)      // 8192
#define FOURH 512

typedef __attribute__((ext_vector_type(8))) short bh8;   // 8 bf16 in 4 VGPRs
typedef __attribute__((ext_vector_type(4))) float fv4;   // MFMA accumulator

__device__ __forceinline__ float frcp(float x){ return __builtin_amdgcn_rcpf(x); }
__device__ __forceinline__ float sigmoidf_(float x){
    return frcp(1.0f + __expf(-x));
}
__device__ __forceinline__ float tanhf_(float x){
    float t = __expf(2.0f * x);
    return 1.0f - 2.0f * frcp(t + 1.0f);   // rcp(inf)=0 -> saturates to +/-1
}
__device__ __forceinline__ unsigned short f2bf(float f){
    __hip_bfloat16 h = __float2bfloat16(f);   // RNE
    union { __hip_bfloat16 b; unsigned short u; } cv; cv.b = h;
    return cv.u;
}

// LDS-only barrier: orders ds ops across the block WITHOUT draining vmcnt.
__device__ __forceinline__ void lds_sync(){
    asm volatile("s_waitcnt lgkmcnt(0)" ::: "memory");
    __builtin_amdgcn_s_barrier();
    __builtin_amdgcn_sched_barrier(0);
}

// ---------------- kernel A: xw = inputs @ lstm_kernel + bias ----------------
// Output layout: xw[row][n*4 + g]  (gate-interleaved per neuron).
__global__ __launch_bounds__(512) void k_xw(const float* __restrict__ inp,
        const float* __restrict__ Wk, const float* __restrict__ bias,
        float* __restrict__ xw){
    __shared__ float in_s[8 * DD];
    int tid = threadIdx.x;
    int r0 = blockIdx.x * 8;
    in_s[tid] = inp[(size_t)r0 * DD + tid];
    __syncthreads();
    int j = tid;                       // original column g*128 + n
    int n = j & 127, g = j >> 7;
    float wreg[DD];
    #pragma unroll
    for (int d = 0; d < DD; ++d) wreg[d] = Wk[d * FOURH + j];
    float bv = bias[j];
    const float4* in4 = reinterpret_cast<const float4*>(in_s);
    #pragma unroll
    for (int r = 0; r < 8; ++r){
        float acc = bv;
        #pragma unroll
        for (int q = 0; q < DD/4; ++q){
            float4 iv = in4[r*(DD/4) + q];
            acc = fmaf(iv.x, wreg[4*q+0], acc);
            acc = fmaf(iv.y, wreg[4*q+1], acc);
            acc = fmaf(iv.z, wreg[4*q+2], acc);
            acc = fmaf(iv.w, wreg[4*q+3], acc);
        }
        xw[(size_t)(r0 + r) * FOURH + n*4 + g] = acc;
    }
}

// ======================= shared scan body (R7, proven) =======================
// CTRL_STRIDE: element stride between consecutive timesteps of one batch row.
// SIGNAL: if wm != nullptr, publish watermark every 16 steps (release, agent).
template<int CTRL_STRIDE>
__device__ __forceinline__ void scan_body(const float* __restrict__ xw,
        const float* __restrict__ Rk, float* __restrict__ ctrl,
        unsigned int* wm, unsigned short* hbuf0, unsigned short* hbuf1,
        int b, int tid){
    const int w  = tid >> 6;     // wave 0..7
    const int l  = tid & 63;
    const int q  = l >> 4;       // k-group 0..3
    const int lo = l & 15;       // A-row / C-col
    if (tid < HH){ hbuf0[tid] = 0; hbuf1[tid] = 0; }
    bh8 bf[4][4];
    #pragma unroll
    for (int Ti = 0; Ti < 4; ++Ti){
        const int col = Ti*128 + w*16 + lo;
        #pragma unroll
        for (int kk = 0; kk < 4; ++kk){
            union { unsigned short us[8]; bh8 v; } u;
            #pragma unroll
            for (int j = 0; j < 8; ++j)
                u.us[j] = f2bf(Rk[(size_t)(kk*32 + q*8 + j)*FOURH + col]);
            bf[Ti][kk] = u.v;
        }
    }
    const bool upd = (q == 0);
    const bool rdh = (lo == 0);
    const int  n   = w*16 + lo;
    const float4* xb4 = reinterpret_cast<const float4*>(xw) + (size_t)b*TT*HH + n;
    float* cptr = ctrl + (size_t)b*TT*CTRL_STRIDE + n;
    float c0 = 0.0f;
    float4 x0 = {0,0,0,0}, x1 = {0,0,0,0}, xp0 = {0,0,0,0}, xp1 = {0,0,0,0};
    if (upd){ x0 = xb4[0]; x1 = xb4[(size_t)HH]; }
    union AU { uint4 u; bh8 v; };
    AU a0, a1, a2, a3;
    a0.u = make_uint4(0u,0u,0u,0u); a1.u = a0.u; a2.u = a0.u; a3.u = a0.u;
    const fv4 zz = {0.f, 0.f, 0.f, 0.f};
    __syncthreads();

#define MFMA16() \
        fv4 z0 = __builtin_amdgcn_mfma_f32_16x16x32_bf16(a0.v, bf[0][0], zz, 0,0,0); \
        fv4 z1 = __builtin_amdgcn_mfma_f32_16x16x32_bf16(a0.v, bf[1][0], zz, 0,0,0); \
        fv4 z2 = __builtin_amdgcn_mfma_f32_16x16x32_bf16(a0.v, bf[2][0], zz, 0,0,0); \
        fv4 z3 = __builtin_amdgcn_mfma_f32_16x16x32_bf16(a0.v, bf[3][0], zz, 0,0,0); \
        z0 = __builtin_amdgcn_mfma_f32_16x16x32_bf16(a1.v, bf[0][1], z0, 0,0,0); \
        z1 = __builtin_amdgcn_mfma_f32_16x16x32_bf16(a1.v, bf[1][1], z1, 0,0,0); \
        z2 = __builtin_amdgcn_mfma_f32_16x16x32_bf16(a1.v, bf[2][1], z2, 0,0,0); \
        z3 = __builtin_amdgcn_mfma_f32_16x16x32_bf16(a1.v, bf[3][1], z3, 0,0,0); \
        z0 = __builtin_amdgcn_mfma_f32_16x16x32_bf16(a2.v, bf[0][2], z0, 0,0,0); \
        z1 = __builtin_amdgcn_mfma_f32_16x16x32_bf16(a2.v, bf[1][2], z1, 0,0,0); \
        z2 = __builtin_amdgcn_mfma_f32_16x16x32_bf16(a2.v, bf[2][2], z2, 0,0,0); \
        z3 = __builtin_amdgcn_mfma_f32_16x16x32_bf16(a2.v, bf[3][2], z3, 0,0,0); \
        z0 = __builtin_amdgcn_mfma_f32_16x16x32_bf16(a3.v, bf[0][3], z0, 0,0,0); \
        z1 = __builtin_amdgcn_mfma_f32_16x16x32_bf16(a3.v, bf[1][3], z1, 0,0,0); \
        z2 = __builtin_amdgcn_mfma_f32_16x16x32_bf16(a3.v, bf[2][3], z2, 0,0,0); \
        z3 = __builtin_amdgcn_mfma_f32_16x16x32_bf16(a3.v, bf[3][3], z3, 0,0,0);

    for (int t = 0; t < TT; t += 2){
        // ---- substep A: time t; read hbuf0, write hbuf1 ----
        if (rdh){
            const uint4* hr = reinterpret_cast<const uint4*>(hbuf0);
            a0.u = hr[q]; a1.u = hr[q+4]; a2.u = hr[q+8]; a3.u = hr[q+12];
        }
        {
            const int tn = (t+2 < TT) ? t+2 : TT-1;
            if (upd) xp0 = xb4[(size_t)tn * HH];
        }
        {
            MFMA16();
            if (upd){
                float ig = sigmoidf_(z0[0] + x0.x);
                float fg = sigmoidf_(z1[0] + x0.y);
                float gg = tanhf_   (z2[0] + x0.z);
                float og = sigmoidf_(z3[0] + x0.w);
                c0 = fg * c0 + ig * gg;
                float h = og * tanhf_(c0);
                cptr[(size_t)t * CTRL_STRIDE] = h;
                hbuf1[n] = f2bf(h);
            }
        }
        lds_sync();
        // ---- substep B: time t+1; read hbuf1, write hbuf0 ----
        if (rdh){
            const uint4* hr = reinterpret_cast<const uint4*>(hbuf1);
            a0.u = hr[q]; a1.u = hr[q+4]; a2.u = hr[q+8]; a3.u = hr[q+12];
        }
        {
            const int tn = (t+3 < TT) ? t+3 : TT-1;
            if (upd) xp1 = xb4[(size_t)tn * HH];
        }
        {
            MFMA16();
            if (upd){
                float ig = sigmoidf_(z0[0] + x1.x);
                float fg = sigmoidf_(z1[0] + x1.y);
                float gg = tanhf_   (z2[0] + x1.z);
                float og = sigmoidf_(z3[0] + x1.w);
                c0 = fg * c0 + ig * gg;
                float h = og * tanhf_(c0);
                cptr[(size_t)(t+1) * CTRL_STRIDE] = h;
                hbuf0[n] = f2bf(h);
            }
        }
        x0 = xp0; x1 = xp1;
        lds_sync();
        if (wm && ((t & 15) == 14)){
            __syncthreads();   // all waves drain vmcnt -> ctrl stores in L2
            if (tid == 0)
                __hip_atomic_store(&wm[b], (unsigned)(t+2),
                                   __ATOMIC_RELEASE, __HIP_MEMORY_SCOPE_AGENT);
        }
    }
#undef MFMA16
}

// ---------------- path-B scan kernel (ctrl in d_ws, stride HH) --------------
__global__ __launch_bounds__(512, 2) void k_scan(const float* __restrict__ xw,
        const float* __restrict__ Rk, float* __restrict__ ctrl){
    __shared__ __align__(16) unsigned short hbuf0[HH];
    __shared__ __align__(16) unsigned short hbuf1[HH];
    scan_body<HH>(xw, Rk, ctrl, nullptr, hbuf0, hbuf1, blockIdx.x, threadIdx.x);
}

// ---------------- path-B heads kernel (R9, standalone, 128 thr) -------------
__device__ __forceinline__ float blocksum128(float v, float* red){
    #pragma unroll
    for (int o = 1; o < 64; o <<= 1) v += __shfl_xor(v, o, 64);
    int tid = threadIdx.x;
    if ((tid & 63) == 0) red[tid >> 6] = v;
    __syncthreads();
    float s = red[0] + red[1];
    __syncthreads();
    return s;
}

__global__ __launch_bounds__(128) void k_heads(const float* __restrict__ ctrl,
        const float* __restrict__ memory,
        const float* __restrict__ rWk, const float* __restrict__ rbk,
        const float* __restrict__ wWk, const float* __restrict__ wbk,
        const float* __restrict__ wWe, const float* __restrict__ wbe,
        const float* __restrict__ wWa, const float* __restrict__ wba,
        float* __restrict__ out, float* __restrict__ outmem){
    __shared__ float mem0[SS * MSZ];
    __shared__ float cs[HH];
    __shared__ float rn[SS];
    __shared__ float khat[4][MSZ];
    __shared__ float ea[4][MSZ];
    __shared__ float wrd[2][SS];
    __shared__ float red[2];
    __shared__ float pz[160];
    int tid = threadIdx.x;
    int bt = blockIdx.x;
    for (int idx = tid; idx < SS * MSZ; idx += 128) mem0[idx] = memory[idx];
    if (tid < HH){
        float v = ctrl[(size_t)bt * HH + tid];
        cs[tid] = v;
        out[(size_t)bt * 168 + tid] = v;
    }
    __syncthreads();
    if (tid < SS){
        float s2 = 0.0f;
        #pragma unroll
        for (int m = 0; m < MSZ; ++m){ float v = mem0[tid*MSZ + m]; s2 = fmaf(v, v, s2); }
        rn[tid] = rsqrtf(fmaxf(s2, 1e-12f));
    }
    for (int j = tid; j < 160; j += 128){
        int p = j / MSZ, m = j % MSZ;
        const float* Wp; const float* bp;
        switch (p){
            case 0:  Wp = rWk;            bp = rbk;        break;
            case 1:  Wp = rWk + HH*MSZ;   bp = rbk + MSZ;  break;
            case 2:  Wp = wWk;            bp = wbk;        break;
            case 3:  Wp = wWk + HH*MSZ;   bp = wbk + MSZ;  break;
            case 4:  Wp = wWe;            bp = wbe;        break;
            case 5:  Wp = wWe + HH*MSZ;   bp = wbe + MSZ;  break;
            case 6:  Wp = wWa;            bp = wba;        break;
            default: Wp = wWa + HH*MSZ;   bp = wba + MSZ;  break;
        }
        float acc = bp[m];
        const float* wcol = Wp + m;
        #pragma unroll 16
        for (int k = 0; k < HH; ++k)
            acc = fmaf(cs[k], wcol[k*MSZ], acc);
        pz[j] = acc;
    }
    __syncthreads();
    {
        int g = tid >> 5, lm = tid & 31;
        float z = (lm < MSZ) ? pz[g*MSZ + lm] : 0.0f;
        float e = (lm < MSZ) ? __expf(z) : 0.0f;
        float ssum = e;
        #pragma unroll
        for (int o = 1; o < 32; o <<= 1) ssum += __shfl_xor(ssum, o, 32);
        float kv = e / ssum;
        float qs = kv * kv;
        #pragma unroll
        for (int o = 1; o < 32; o <<= 1) qs += __shfl_xor(qs, o, 32);
        float kn = kv * rsqrtf(fmaxf(qs, 1e-12f));
        if (lm < MSZ) khat[g][lm] = kn;
        float z2 = (lm < MSZ) ? pz[80 + g*MSZ + lm] : 0.0f;
        float v2 = (g < 2) ? sigmoidf_(z2) : z2;
        if (lm < MSZ) ea[g][lm] = v2;
    }
    __syncthreads();
    bool act = tid < SS;
    int s = tid;
    float d0 = 0.f, d1 = 0.f, dw = 0.f;
    if (act){
        #pragma unroll
        for (int m = 0; m < MSZ; ++m){
            float mv = mem0[s*MSZ + m];
            d0 = fmaf(khat[0][m], mv, d0);
            d1 = fmaf(khat[1][m], mv, d1);
            dw = fmaf(khat[2][m], mv, dw);
        }
    }
    float rns = act ? rn[s] : 0.0f;
    float e0 = act ? __expf(-rns * d0) : 0.0f;
    float e1 = act ? __expf(-rns * d1) : 0.0f;
    float ew = act ? __expf(-rns * dw) : 0.0f;
    float sum0 = blocksum128(e0, red);
    float sum1 = blocksum128(e1, red);
    float sumw = blocksum128(ew, red);
    if (act){ wrd[0][s] = e0 / sum0; wrd[1][s] = e1 / sum1; }
    float w0 = ew / sumw;
    float m1[MSZ];
    float n1 = 0.f, dkw = 0.f;
    if (act){
        #pragma unroll
        for (int m = 0; m < MSZ; ++m){
            float mv = mem0[s*MSZ + m];
            float v = fmaf(-w0 * ea[0][m], mv, mv);
            v = fmaf(w0, ea[2][m], v);
            m1[m] = v;
            n1 = fmaf(v, v, n1);
            dkw = fmaf(khat[3][m], v, dkw);
        }
    }
    float rn1 = rsqrtf(fmaxf(n1, 1e-12f));
    float e1w = act ? __expf(-rn1 * dkw) : 0.0f;
    float sum1w = blocksum128(e1w, red);
    float w1 = e1w / sum1w;
    if (act){
        float buf[MSZ];
        #pragma unroll
        for (int m = 0; m < MSZ; ++m){
            float v = m1[m];
            float v2 = fmaf(-w1 * ea[1][m], v, v);
            v2 = fmaf(w1, ea[3][m], v2);
            buf[m] = v2;
        }
        float4* dst = reinterpret_cast<float4*>(outmem + ((size_t)bt * SS + s) * MSZ);
        #pragma unroll
        for (int q = 0; q < MSZ/4; ++q)
            dst[q] = make_float4(buf[4*q], buf[4*q+1], buf[4*q+2], buf[4*q+3]);
    }
    __syncthreads();
    if (tid < 2 * MSZ){
        int hd = tid / MSZ, m = tid % MSZ;
        float acc = 0.0f;
        for (int s2 = 0; s2 < SS; ++s2)
            acc = fmaf(wrd[hd][s2], mem0[s2*MSZ + m], acc);
        out[(size_t)bt * 168 + 128 + hd*MSZ + m] = acc;
    }
}

// ---------------- path-A mega kernel: scan (blocks 0..15) + heads consumers -
__device__ __forceinline__ float bsum_slot(float v, float* red2){
    #pragma unroll
    for (int o = 1; o < 64; o <<= 1) v += __shfl_xor(v, o, 64);
    int tid = threadIdx.x;
    if ((tid & 63) == 0) red2[(tid >> 6) & 1] = v;
    __syncthreads();
    float s = red2[0] + red2[1];
    __syncthreads();
    return s;
}

__global__ __launch_bounds__(512, 2) void k_mega(const float* __restrict__ xw,
        const float* __restrict__ Rk, const float* __restrict__ memory,
        const float* __restrict__ rWk, const float* __restrict__ rbk,
        const float* __restrict__ wWk, const float* __restrict__ wbk,
        const float* __restrict__ wWe, const float* __restrict__ wbe,
        const float* __restrict__ wWa, const float* __restrict__ wba,
        float* __restrict__ out, float* __restrict__ outmem,
        unsigned int* wm){
    __shared__ __align__(16) unsigned short hbuf0[HH];
    __shared__ __align__(16) unsigned short hbuf1[HH];
    __shared__ float mem0[SS * MSZ];
    __shared__ float rn_s[SS];
    __shared__ float cs4[4][HH];
    __shared__ float pz4[4][160];
    __shared__ float kh4[4][4][MSZ];
    __shared__ float ea4[4][4][MSZ];
    __shared__ float wr4[4][2][SS];
    __shared__ float rd4[4][2];
    const int tid = threadIdx.x;
    if (blockIdx.x < BB){
        // ctrl goes straight into out[:,0:128] (stride 168); signal watermark.
        scan_body<168>(xw, Rk, out, wm, hbuf0, hbuf1, blockIdx.x, tid);
        return;
    }
    // ===================== consumer: 4 head-items per sweep =================
    for (int idx = tid; idx < SS * MSZ; idx += 512) mem0[idx] = memory[idx];
    __syncthreads();
    if (tid < SS){
        float s2 = 0.0f;
        #pragma unroll
        for (int m = 0; m < MSZ; ++m){ float v = mem0[tid*MSZ + m]; s2 = fmaf(v, v, s2); }
        rn_s[tid] = rsqrtf(fmaxf(s2, 1e-12f));
    }
    __syncthreads();
    const int t128 = tid & 127;
    const int slot = tid >> 7;
    const int cb   = blockIdx.x - BB;      // 0..239
    float* red2 = rd4[slot];
    for (int sweep = 0; sweep < 9; ++sweep){
        const int it = sweep*960 + cb*4 + slot;     // item: t = it>>4, b = it&15
        const bool valid = (it < NROW);
        const int bb = it & 15;
        const int tt = it >> 4;
        const size_t row = valid ? ((size_t)bb*TT + tt) : 0;   // out/outmem row
        if (tid == 0){
            #pragma unroll
            for (int s4 = 0; s4 < 4; ++s4){
                const int it2 = sweep*960 + cb*4 + s4;
                if (it2 < NROW){
                    const int b2 = it2 & 15, t2 = it2 >> 4;
                    while ((int)__hip_atomic_load(&wm[b2], __ATOMIC_ACQUIRE,
                                                  __HIP_MEMORY_SCOPE_AGENT) <= t2)
                        __builtin_amdgcn_s_sleep(2);
                }
            }
        }
        __syncthreads();
        cs4[slot][t128] = valid ? out[row*168 + t128] : 0.0f;
        __syncthreads();
        // fused proj
        for (int j = t128; j < 160; j += 128){
            int p = j / MSZ, m = j % MSZ;
            const float* Wp; const float* bp;
            switch (p){
                case 0:  Wp = rWk;            bp = rbk;        break;
                case 1:  Wp = rWk + HH*MSZ;   bp = rbk + MSZ;  break;
                case 2:  Wp = wWk;            bp = wbk;        break;
                case 3:  Wp = wWk + HH*MSZ;   bp = wbk + MSZ;  break;
                case 4:  Wp = wWe;            bp = wbe;        break;
                case 5:  Wp = wWe + HH*MSZ;   bp = wbe + MSZ;  break;
                case 6:  Wp = wWa;            bp = wba;        break;
                default: Wp = wWa + HH*MSZ;   bp = wba + MSZ;  break;
            }
            float acc = bp[m];
            const float* wcol = Wp + m;
            #pragma unroll 16
            for (int k = 0; k < HH; ++k)
                acc = fmaf(cs4[slot][k], wcol[k*MSZ], acc);
            pz4[slot][j] = acc;
        }
        __syncthreads();
        {
            int g = t128 >> 5, lm = t128 & 31;
            float z = (lm < MSZ) ? pz4[slot][g*MSZ + lm] : 0.0f;
            float e = (lm < MSZ) ? __expf(z) : 0.0f;
            float ssum = e;
            #pragma unroll
            for (int o = 1; o < 32; o <<= 1) ssum += __shfl_xor(ssum, o, 32);
            float kv = e / ssum;
            float qs = kv * kv;
            #pragma unroll
            for (int o = 1; o < 32; o <<= 1) qs += __shfl_xor(qs, o, 32);
            float kn = kv * rsqrtf(fmaxf(qs, 1e-12f));
            if (lm < MSZ) kh4[slot][g][lm] = kn;
            float z2 = (lm < MSZ) ? pz4[slot][80 + g*MSZ + lm] : 0.0f;
            float v2 = (g < 2) ? sigmoidf_(z2) : z2;
            if (lm < MSZ) ea4[slot][g][lm] = v2;
        }
        __syncthreads();
        bool act = t128 < SS;
        int s = t128;
        float d0 = 0.f, d1 = 0.f, dw = 0.f;
        if (act){
            #pragma unroll
            for (int m = 0; m < MSZ; ++m){
                float mv = mem0[s*MSZ + m];
                d0 = fmaf(kh4[slot][0][m], mv, d0);
                d1 = fmaf(kh4[slot][1][m], mv, d1);
                dw = fmaf(kh4[slot][2][m], mv, dw);
            }
        }
        float rns = act ? rn_s[s] : 0.0f;
        float e0 = act ? __expf(-rns * d0) : 0.0f;
        float e1 = act ? __expf(-rns * d1) : 0.0f;
        float ew = act ? __expf(-rns * dw) : 0.0f;
        float sum0 = bsum_slot(e0, red2);
        float sum1 = bsum_slot(e1, red2);
        float sumw = bsum_slot(ew, red2);
        if (act){ wr4[slot][0][s] = e0 / sum0; wr4[slot][1][s] = e1 / sum1; }
        float w0 = ew / sumw;
        float m1[MSZ];
        float n1 = 0.f, dkw = 0.f;
        if (act){
            #pragma unroll
            for (int m = 0; m < MSZ; ++m){
                float mv = mem0[s*MSZ + m];
                float v = fmaf(-w0 * ea4[slot][0][m], mv, mv);
                v = fmaf(w0, ea4[slot][2][m], v);
                m1[m] = v;
                n1 = fmaf(v, v, n1);
                dkw = fmaf(kh4[slot][3][m], v, dkw);
            }
        }
        float rn1 = rsqrtf(fmaxf(n1, 1e-12f));
        float e1w = act ? __expf(-rn1 * dkw) : 0.0f;
        float sum1w = bsum_slot(e1w, red2);
        float w1 = e1w / sum1w;
        if (act && valid){
            float buf[MSZ];
            #pragma unroll
            for (int m = 0; m < MSZ; ++m){
                float v = m1[m];
                float v2 = fmaf(-w1 * ea4[slot][1][m], v, v);
                v2 = fmaf(w1, ea4[slot][3][m], v2);
                buf[m] = v2;
            }
            float4* dst = reinterpret_cast<float4*>(outmem + (row*SS + s)*MSZ);
            #pragma unroll
            for (int q = 0; q < MSZ/4; ++q)
                dst[q] = make_float4(buf[4*q], buf[4*q+1], buf[4*q+2], buf[4*q+3]);
        }
        __syncthreads();
        if (t128 < 2*MSZ && valid){
            int hd = t128 / MSZ, m = t128 % MSZ;
            float acc = 0.0f;
            for (int s2 = 0; s2 < SS; ++s2)
                acc = fmaf(wr4[slot][hd][s2], mem0[s2*MSZ + m], acc);
            out[row*168 + 128 + hd*MSZ + m] = acc;
        }
        __syncthreads();
    }
}

extern "C" void kernel_launch(void* const* d_in, const int* in_sizes, int n_in,
                              void* d_out, int out_size, void* d_ws, size_t ws_size,
                              hipStream_t stream){
    const float* inputs = (const float*)d_in[0];
    const float* memory = (const float*)d_in[1];
    const float* Wk     = (const float*)d_in[2];
    const float* Rk     = (const float*)d_in[3];
    const float* bias   = (const float*)d_in[4];
    const float* rWk    = (const float*)d_in[5];
    const float* rbk    = (const float*)d_in[6];
    const float* wWk    = (const float*)d_in[7];
    const float* wbk    = (const float*)d_in[8];
    const float* wWe    = (const float*)d_in[9];
    const float* wbe    = (const float*)d_in[10];
    const float* wWa    = (const float*)d_in[11];
    const float* wba    = (const float*)d_in[12];

    float* out    = (float*)d_out;
    float* outmem = out + (size_t)NROW * 168;
    const size_t XW_BYTES = (size_t)NROW * FOURH * sizeof(float);   // 16.78 MB

    if (ws_size >= XW_BYTES + 256){
        // ---- path A: overlapped producer/consumer mega-kernel ----
        float* xw = (float*)d_ws;
        unsigned int* wm = (unsigned int*)((char*)d_ws + XW_BYTES);
        hipMemsetAsync(wm, 0, 64, stream);
        k_xw  <<<NROW/8, 512, 0, stream>>>(inputs, Wk, bias, xw);
        k_mega<<<256,    512, 0, stream>>>(xw, Rk, memory,
                                           rWk, rbk, wWk, wbk, wWe, wbe, wWa, wba,
                                           out, outmem, wm);
    } else {
        // ---- path B: exact R9 pipeline (xw aliases outmem; ctrl in ws) ----
        float* xw   = outmem;
        float* ctrl = (float*)d_ws;
        k_xw   <<<NROW/8, 512, 0, stream>>>(inputs, Wk, bias, xw);
        k_scan <<<BB,     512, 0, stream>>>(xw, Rk, ctrl);
        k_heads<<<NROW,   128, 0, stream>>>(ctrl, memory,
                                            rWk, rbk, wWk, wbk, wWe, wbe, wWa, wba,
                                            out, outmem);
    }
}

// Round 12
// 483.727 us; speedup vs baseline: 1.0058x; 1.0058x over previous
//
#include <hip/hip_runtime.h>
#include <hip/hip_bf16.h>

#define BB 16
#define TT 512
#define DD 64
#define HH 128
#define SS 100
#define MSZ 20
#define NROW (BB*TT)      // 8192
#define FOURH 512

typedef __attribute__((ext_vector_type(8))) short bh8;   // 8 bf16 in 4 VGPRs
typedef __attribute__((ext_vector_type(4))) float fv4;   // MFMA accumulator

__device__ __forceinline__ float frcp(float x){ return __builtin_amdgcn_rcpf(x); }
__device__ __forceinline__ float sigmoidf_(float x){
    return frcp(1.0f + __expf(-x));
}
__device__ __forceinline__ float tanhf_(float x){
    float t = __expf(2.0f * x);
    return 1.0f - 2.0f * frcp(t + 1.0f);   // rcp(inf)=0 -> saturates to +/-1
}
__device__ __forceinline__ unsigned short f2bf(float f){
    __hip_bfloat16 h = __float2bfloat16(f);   // RNE
    union { __hip_bfloat16 b; unsigned short u; } cv; cv.b = h;
    return cv.u;
}

// LDS-only barrier: orders ds ops across the block WITHOUT draining vmcnt.
__device__ __forceinline__ void lds_sync(){
    asm volatile("s_waitcnt lgkmcnt(0)" ::: "memory");
    __builtin_amdgcn_s_barrier();
    __builtin_amdgcn_sched_barrier(0);
}

// ---------------- kernel A: xw = inputs @ lstm_kernel + bias ----------------
// Output layout: xw[row][n*4 + g]  (gate-interleaved per neuron).
__global__ __launch_bounds__(512) void k_xw(const float* __restrict__ inp,
        const float* __restrict__ Wk, const float* __restrict__ bias,
        float* __restrict__ xw){
    __shared__ float in_s[8 * DD];
    int tid = threadIdx.x;
    int r0 = blockIdx.x * 8;
    in_s[tid] = inp[(size_t)r0 * DD + tid];
    __syncthreads();
    int j = tid;                       // original column g*128 + n
    int n = j & 127, g = j >> 7;
    float wreg[DD];
    #pragma unroll
    for (int d = 0; d < DD; ++d) wreg[d] = Wk[d * FOURH + j];
    float bv = bias[j];
    const float4* in4 = reinterpret_cast<const float4*>(in_s);
    #pragma unroll
    for (int r = 0; r < 8; ++r){
        float acc = bv;
        #pragma unroll
        for (int q = 0; q < DD/4; ++q){
            float4 iv = in4[r*(DD/4) + q];
            acc = fmaf(iv.x, wreg[4*q+0], acc);
            acc = fmaf(iv.y, wreg[4*q+1], acc);
            acc = fmaf(iv.z, wreg[4*q+2], acc);
            acc = fmaf(iv.w, wreg[4*q+3], acc);
        }
        xw[(size_t)(r0 + r) * FOURH + n*4 + g] = acc;
    }
}

// ======================= shared scan body (R7, proven) =======================
template<int CTRL_STRIDE>
__device__ __forceinline__ void scan_body(const float* __restrict__ xw,
        const float* __restrict__ Rk, float* __restrict__ ctrl,
        unsigned int* wm, unsigned short* hbuf0, unsigned short* hbuf1,
        int b, int tid){
    const int w  = tid >> 6;     // wave 0..7
    const int l  = tid & 63;
    const int q  = l >> 4;       // k-group 0..3
    const int lo = l & 15;       // A-row / C-col
    if (tid < HH){ hbuf0[tid] = 0; hbuf1[tid] = 0; }
    bh8 bf[4][4];
    #pragma unroll
    for (int Ti = 0; Ti < 4; ++Ti){
        const int col = Ti*128 + w*16 + lo;
        #pragma unroll
        for (int kk = 0; kk < 4; ++kk){
            union { unsigned short us[8]; bh8 v; } u;
            #pragma unroll
            for (int j = 0; j < 8; ++j)
                u.us[j] = f2bf(Rk[(size_t)(kk*32 + q*8 + j)*FOURH + col]);
            bf[Ti][kk] = u.v;
        }
    }
    const bool upd = (q == 0);
    const bool rdh = (lo == 0);
    const int  n   = w*16 + lo;
    const float4* xb4 = reinterpret_cast<const float4*>(xw) + (size_t)b*TT*HH + n;
    float* cptr = ctrl + (size_t)b*TT*CTRL_STRIDE + n;
    float c0 = 0.0f;
    float4 x0 = {0,0,0,0}, x1 = {0,0,0,0}, xp0 = {0,0,0,0}, xp1 = {0,0,0,0};
    if (upd){ x0 = xb4[0]; x1 = xb4[(size_t)HH]; }
    union AU { uint4 u; bh8 v; };
    AU a0, a1, a2, a3;
    a0.u = make_uint4(0u,0u,0u,0u); a1.u = a0.u; a2.u = a0.u; a3.u = a0.u;
    const fv4 zz = {0.f, 0.f, 0.f, 0.f};
    __syncthreads();

#define MFMA16() \
        fv4 z0 = __builtin_amdgcn_mfma_f32_16x16x32_bf16(a0.v, bf[0][0], zz, 0,0,0); \
        fv4 z1 = __builtin_amdgcn_mfma_f32_16x16x32_bf16(a0.v, bf[1][0], zz, 0,0,0); \
        fv4 z2 = __builtin_amdgcn_mfma_f32_16x16x32_bf16(a0.v, bf[2][0], zz, 0,0,0); \
        fv4 z3 = __builtin_amdgcn_mfma_f32_16x16x32_bf16(a0.v, bf[3][0], zz, 0,0,0); \
        z0 = __builtin_amdgcn_mfma_f32_16x16x32_bf16(a1.v, bf[0][1], z0, 0,0,0); \
        z1 = __builtin_amdgcn_mfma_f32_16x16x32_bf16(a1.v, bf[1][1], z1, 0,0,0); \
        z2 = __builtin_amdgcn_mfma_f32_16x16x32_bf16(a1.v, bf[2][1], z2, 0,0,0); \
        z3 = __builtin_amdgcn_mfma_f32_16x16x32_bf16(a1.v, bf[3][1], z3, 0,0,0); \
        z0 = __builtin_amdgcn_mfma_f32_16x16x32_bf16(a2.v, bf[0][2], z0, 0,0,0); \
        z1 = __builtin_amdgcn_mfma_f32_16x16x32_bf16(a2.v, bf[1][2], z1, 0,0,0); \
        z2 = __builtin_amdgcn_mfma_f32_16x16x32_bf16(a2.v, bf[2][2], z2, 0,0,0); \
        z3 = __builtin_amdgcn_mfma_f32_16x16x32_bf16(a2.v, bf[3][2], z3, 0,0,0); \
        z0 = __builtin_amdgcn_mfma_f32_16x16x32_bf16(a3.v, bf[0][3], z0, 0,0,0); \
        z1 = __builtin_amdgcn_mfma_f32_16x16x32_bf16(a3.v, bf[1][3], z1, 0,0,0); \
        z2 = __builtin_amdgcn_mfma_f32_16x16x32_bf16(a3.v, bf[2][3], z2, 0,0,0); \
        z3 = __builtin_amdgcn_mfma_f32_16x16x32_bf16(a3.v, bf[3][3], z3, 0,0,0);

    for (int t = 0; t < TT; t += 2){
        // ---- substep A: time t; read hbuf0, write hbuf1 ----
        if (rdh){
            const uint4* hr = reinterpret_cast<const uint4*>(hbuf0);
            a0.u = hr[q]; a1.u = hr[q+4]; a2.u = hr[q+8]; a3.u = hr[q+12];
        }
        {
            const int tn = (t+2 < TT) ? t+2 : TT-1;
            if (upd) xp0 = xb4[(size_t)tn * HH];
        }
        {
            MFMA16();
            if (upd){
                float ig = sigmoidf_(z0[0] + x0.x);
                float fg = sigmoidf_(z1[0] + x0.y);
                float gg = tanhf_   (z2[0] + x0.z);
                float og = sigmoidf_(z3[0] + x0.w);
                c0 = fg * c0 + ig * gg;
                float h = og * tanhf_(c0);
                cptr[(size_t)t * CTRL_STRIDE] = h;
                hbuf1[n] = f2bf(h);
            }
        }
        lds_sync();
        // ---- substep B: time t+1; read hbuf1, write hbuf0 ----
        if (rdh){
            const uint4* hr = reinterpret_cast<const uint4*>(hbuf1);
            a0.u = hr[q]; a1.u = hr[q+4]; a2.u = hr[q+8]; a3.u = hr[q+12];
        }
        {
            const int tn = (t+3 < TT) ? t+3 : TT-1;
            if (upd) xp1 = xb4[(size_t)tn * HH];
        }
        {
            MFMA16();
            if (upd){
                float ig = sigmoidf_(z0[0] + x1.x);
                float fg = sigmoidf_(z1[0] + x1.y);
                float gg = tanhf_   (z2[0] + x1.z);
                float og = sigmoidf_(z3[0] + x1.w);
                c0 = fg * c0 + ig * gg;
                float h = og * tanhf_(c0);
                cptr[(size_t)(t+1) * CTRL_STRIDE] = h;
                hbuf0[n] = f2bf(h);
            }
        }
        x0 = xp0; x1 = xp1;
        lds_sync();
        if (wm && ((t & 15) == 14)){
            __syncthreads();   // drain vmcnt -> ctrl stores visible in L2
            if (tid == 0)
                __hip_atomic_store(&wm[b], (unsigned)(t+2),
                                   __ATOMIC_RELEASE, __HIP_MEMORY_SCOPE_AGENT);
        }
    }
#undef MFMA16
}

// ---------------- path-B scan kernel (ctrl in d_ws, stride HH) --------------
__global__ __launch_bounds__(512, 2) void k_scan(const float* __restrict__ xw,
        const float* __restrict__ Rk, float* __restrict__ ctrl){
    __shared__ __align__(16) unsigned short hbuf0[HH];
    __shared__ __align__(16) unsigned short hbuf1[HH];
    scan_body<HH>(xw, Rk, ctrl, nullptr, hbuf0, hbuf1, blockIdx.x, threadIdx.x);
}

// ---------------- path-B heads kernel (R9, standalone, 128 thr) -------------
__device__ __forceinline__ float blocksum128(float v, float* red){
    #pragma unroll
    for (int o = 1; o < 64; o <<= 1) v += __shfl_xor(v, o, 64);
    int tid = threadIdx.x;
    if ((tid & 63) == 0) red[tid >> 6] = v;
    __syncthreads();
    float s = red[0] + red[1];
    __syncthreads();
    return s;
}

__global__ __launch_bounds__(128) void k_heads(const float* __restrict__ ctrl,
        const float* __restrict__ memory,
        const float* __restrict__ rWk, const float* __restrict__ rbk,
        const float* __restrict__ wWk, const float* __restrict__ wbk,
        const float* __restrict__ wWe, const float* __restrict__ wbe,
        const float* __restrict__ wWa, const float* __restrict__ wba,
        float* __restrict__ out, float* __restrict__ outmem){
    __shared__ float mem0[SS * MSZ];
    __shared__ float cs[HH];
    __shared__ float rn[SS];
    __shared__ float khat[4][MSZ];
    __shared__ float ea[4][MSZ];
    __shared__ float wrd[2][SS];
    __shared__ float red[2];
    __shared__ float pz[160];
    int tid = threadIdx.x;
    int bt = blockIdx.x;
    for (int idx = tid; idx < SS * MSZ; idx += 128) mem0[idx] = memory[idx];
    if (tid < HH){
        float v = ctrl[(size_t)bt * HH + tid];
        cs[tid] = v;
        out[(size_t)bt * 168 + tid] = v;
    }
    __syncthreads();
    if (tid < SS){
        float s2 = 0.0f;
        #pragma unroll
        for (int m = 0; m < MSZ; ++m){ float v = mem0[tid*MSZ + m]; s2 = fmaf(v, v, s2); }
        rn[tid] = rsqrtf(fmaxf(s2, 1e-12f));
    }
    for (int j = tid; j < 160; j += 128){
        int p = j / MSZ, m = j % MSZ;
        const float* Wp; const float* bp;
        switch (p){
            case 0:  Wp = rWk;            bp = rbk;        break;
            case 1:  Wp = rWk + HH*MSZ;   bp = rbk + MSZ;  break;
            case 2:  Wp = wWk;            bp = wbk;        break;
            case 3:  Wp = wWk + HH*MSZ;   bp = wbk + MSZ;  break;
            case 4:  Wp = wWe;            bp = wbe;        break;
            case 5:  Wp = wWe + HH*MSZ;   bp = wbe + MSZ;  break;
            case 6:  Wp = wWa;            bp = wba;        break;
            default: Wp = wWa + HH*MSZ;   bp = wba + MSZ;  break;
        }
        float acc = bp[m];
        const float* wcol = Wp + m;
        #pragma unroll 16
        for (int k = 0; k < HH; ++k)
            acc = fmaf(cs[k], wcol[k*MSZ], acc);
        pz[j] = acc;
    }
    __syncthreads();
    {
        int g = tid >> 5, lm = tid & 31;
        float z = (lm < MSZ) ? pz[g*MSZ + lm] : 0.0f;
        float e = (lm < MSZ) ? __expf(z) : 0.0f;
        float ssum = e;
        #pragma unroll
        for (int o = 1; o < 32; o <<= 1) ssum += __shfl_xor(ssum, o, 32);
        float kv = e / ssum;
        float qs = kv * kv;
        #pragma unroll
        for (int o = 1; o < 32; o <<= 1) qs += __shfl_xor(qs, o, 32);
        float kn = kv * rsqrtf(fmaxf(qs, 1e-12f));
        if (lm < MSZ) khat[g][lm] = kn;
        float z2 = (lm < MSZ) ? pz[80 + g*MSZ + lm] : 0.0f;
        float v2 = (g < 2) ? sigmoidf_(z2) : z2;
        if (lm < MSZ) ea[g][lm] = v2;
    }
    __syncthreads();
    bool act = tid < SS;
    int s = tid;
    float d0 = 0.f, d1 = 0.f, dw = 0.f;
    if (act){
        #pragma unroll
        for (int m = 0; m < MSZ; ++m){
            float mv = mem0[s*MSZ + m];
            d0 = fmaf(khat[0][m], mv, d0);
            d1 = fmaf(khat[1][m], mv, d1);
            dw = fmaf(khat[2][m], mv, dw);
        }
    }
    float rns = act ? rn[s] : 0.0f;
    float e0 = act ? __expf(-rns * d0) : 0.0f;
    float e1 = act ? __expf(-rns * d1) : 0.0f;
    float ew = act ? __expf(-rns * dw) : 0.0f;
    float sum0 = blocksum128(e0, red);
    float sum1 = blocksum128(e1, red);
    float sumw = blocksum128(ew, red);
    if (act){ wrd[0][s] = e0 / sum0; wrd[1][s] = e1 / sum1; }
    float w0 = ew / sumw;
    float m1[MSZ];
    float n1 = 0.f, dkw = 0.f;
    if (act){
        #pragma unroll
        for (int m = 0; m < MSZ; ++m){
            float mv = mem0[s*MSZ + m];
            float v = fmaf(-w0 * ea[0][m], mv, mv);
            v = fmaf(w0, ea[2][m], v);
            m1[m] = v;
            n1 = fmaf(v, v, n1);
            dkw = fmaf(khat[3][m], v, dkw);
        }
    }
    float rn1 = rsqrtf(fmaxf(n1, 1e-12f));
    float e1w = act ? __expf(-rn1 * dkw) : 0.0f;
    float sum1w = blocksum128(e1w, red);
    float w1 = e1w / sum1w;
    if (act){
        float buf[MSZ];
        #pragma unroll
        for (int m = 0; m < MSZ; ++m){
            float v = m1[m];
            float v2 = fmaf(-w1 * ea[1][m], v, v);
            v2 = fmaf(w1, ea[3][m], v2);
            buf[m] = v2;
        }
        float4* dst = reinterpret_cast<float4*>(outmem + ((size_t)bt * SS + s) * MSZ);
        #pragma unroll
        for (int q = 0; q < MSZ/4; ++q)
            dst[q] = make_float4(buf[4*q], buf[4*q+1], buf[4*q+2], buf[4*q+3]);
    }
    __syncthreads();
    if (tid < 2 * MSZ){
        int hd = tid / MSZ, m = tid % MSZ;
        float acc = 0.0f;
        for (int s2 = 0; s2 < SS; ++s2)
            acc = fmaf(wrd[hd][s2], mem0[s2*MSZ + m], acc);
        out[(size_t)bt * 168 + 128 + hd*MSZ + m] = acc;
    }
}

// ---------------- path-A mega kernel: scan (blocks 0..15) + heads consumers -
// 84 KB of (unused) dynamic LDS per block forces ONE block per CU so the 16
// scan blocks own their CUs (R7 environment) and never share with consumers.
__device__ __forceinline__ float bsum_slot(float v, float* red2){
    #pragma unroll
    for (int o = 1; o < 64; o <<= 1) v += __shfl_xor(v, o, 64);
    int tid = threadIdx.x;
    if ((tid & 63) == 0) red2[(tid >> 6) & 1] = v;
    __syncthreads();
    float s = red2[0] + red2[1];
    __syncthreads();
    return s;
}

__global__ __launch_bounds__(512, 2) void k_mega(const float* __restrict__ xw,
        const float* __restrict__ Rk, const float* __restrict__ memory,
        const float* __restrict__ rWk, const float* __restrict__ rbk,
        const float* __restrict__ wWk, const float* __restrict__ wbk,
        const float* __restrict__ wWe, const float* __restrict__ wbe,
        const float* __restrict__ wWa, const float* __restrict__ wba,
        float* __restrict__ out, float* __restrict__ outmem,
        unsigned int* wm){
    extern __shared__ char occupancy_pad[];   // sized 84 KB at launch; unused
    __shared__ __align__(16) unsigned short hbuf0[HH];
    __shared__ __align__(16) unsigned short hbuf1[HH];
    __shared__ float mem0[SS * MSZ];
    __shared__ float rn_s[SS];
    __shared__ float cs4[4][HH];
    __shared__ float pz4[4][160];
    __shared__ float kh4[4][4][MSZ];
    __shared__ float ea4[4][4][MSZ];
    __shared__ float wr4[4][2][SS];
    __shared__ float rd4[4][2];
    const int tid = threadIdx.x;
    if (tid == 0) occupancy_pad[0] = 0;       // keep the allocation live
    if (blockIdx.x < BB){
        scan_body<168>(xw, Rk, out, wm, hbuf0, hbuf1, blockIdx.x, tid);
        return;
    }
    // ===================== consumer: 4 head-items per sweep =================
    for (int idx = tid; idx < SS * MSZ; idx += 512) mem0[idx] = memory[idx];
    __syncthreads();
    if (tid < SS){
        float s2 = 0.0f;
        #pragma unroll
        for (int m = 0; m < MSZ; ++m){ float v = mem0[tid*MSZ + m]; s2 = fmaf(v, v, s2); }
        rn_s[tid] = rsqrtf(fmaxf(s2, 1e-12f));
    }
    __syncthreads();
    const int t128 = tid & 127;
    const int slot = tid >> 7;
    const int cb   = blockIdx.x - BB;      // 0..239
    float* red2 = rd4[slot];
    for (int sweep = 0; sweep < 9; ++sweep){
        const int it = sweep*960 + cb*4 + slot;     // item: t = it>>4, b = it&15
        const bool valid = (it < NROW);
        const int bb = it & 15;
        const int tt = it >> 4;
        const size_t row = valid ? ((size_t)bb*TT + tt) : 0;
        if (tid == 0){
            #pragma unroll
            for (int s4 = 0; s4 < 4; ++s4){
                const int it2 = sweep*960 + cb*4 + s4;
                if (it2 < NROW){
                    const int b2 = it2 & 15, t2 = it2 >> 4;
                    while ((int)__hip_atomic_load(&wm[b2], __ATOMIC_ACQUIRE,
                                                  __HIP_MEMORY_SCOPE_AGENT) <= t2)
                        __builtin_amdgcn_s_sleep(2);
                }
            }
        }
        __syncthreads();
        cs4[slot][t128] = valid ? out[row*168 + t128] : 0.0f;
        __syncthreads();
        for (int j = t128; j < 160; j += 128){
            int p = j / MSZ, m = j % MSZ;
            const float* Wp; const float* bp;
            switch (p){
                case 0:  Wp = rWk;            bp = rbk;        break;
                case 1:  Wp = rWk + HH*MSZ;   bp = rbk + MSZ;  break;
                case 2:  Wp = wWk;            bp = wbk;        break;
                case 3:  Wp = wWk + HH*MSZ;   bp = wbk + MSZ;  break;
                case 4:  Wp = wWe;            bp = wbe;        break;
                case 5:  Wp = wWe + HH*MSZ;   bp = wbe + MSZ;  break;
                case 6:  Wp = wWa;            bp = wba;        break;
                default: Wp = wWa + HH*MSZ;   bp = wba + MSZ;  break;
            }
            float acc = bp[m];
            const float* wcol = Wp + m;
            #pragma unroll 16
            for (int k = 0; k < HH; ++k)
                acc = fmaf(cs4[slot][k], wcol[k*MSZ], acc);
            pz4[slot][j] = acc;
        }
        __syncthreads();
        {
            int g = t128 >> 5, lm = t128 & 31;
            float z = (lm < MSZ) ? pz4[slot][g*MSZ + lm] : 0.0f;
            float e = (lm < MSZ) ? __expf(z) : 0.0f;
            float ssum = e;
            #pragma unroll
            for (int o = 1; o < 32; o <<= 1) ssum += __shfl_xor(ssum, o, 32);
            float kv = e / ssum;
            float qs = kv * kv;
            #pragma unroll
            for (int o = 1; o < 32; o <<= 1) qs += __shfl_xor(qs, o, 32);
            float kn = kv * rsqrtf(fmaxf(qs, 1e-12f));
            if (lm < MSZ) kh4[slot][g][lm] = kn;
            float z2 = (lm < MSZ) ? pz4[slot][80 + g*MSZ + lm] : 0.0f;
            float v2 = (g < 2) ? sigmoidf_(z2) : z2;
            if (lm < MSZ) ea4[slot][g][lm] = v2;
        }
        __syncthreads();
        bool act = t128 < SS;
        int s = t128;
        float d0 = 0.f, d1 = 0.f, dw = 0.f;
        if (act){
            #pragma unroll
            for (int m = 0; m < MSZ; ++m){
                float mv = mem0[s*MSZ + m];
                d0 = fmaf(kh4[slot][0][m], mv, d0);
                d1 = fmaf(kh4[slot][1][m], mv, d1);
                dw = fmaf(kh4[slot][2][m], mv, dw);
            }
        }
        float rns = act ? rn_s[s] : 0.0f;
        float e0 = act ? __expf(-rns * d0) : 0.0f;
        float e1 = act ? __expf(-rns * d1) : 0.0f;
        float ew = act ? __expf(-rns * dw) : 0.0f;
        float sum0 = bsum_slot(e0, red2);
        float sum1 = bsum_slot(e1, red2);
        float sumw = bsum_slot(ew, red2);
        if (act){ wr4[slot][0][s] = e0 / sum0; wr4[slot][1][s] = e1 / sum1; }
        float w0 = ew / sumw;
        float m1[MSZ];
        float n1 = 0.f, dkw = 0.f;
        if (act){
            #pragma unroll
            for (int m = 0; m < MSZ; ++m){
                float mv = mem0[s*MSZ + m];
                float v = fmaf(-w0 * ea4[slot][0][m], mv, mv);
                v = fmaf(w0, ea4[slot][2][m], v);
                m1[m] = v;
                n1 = fmaf(v, v, n1);
                dkw = fmaf(kh4[slot][3][m], v, dkw);
            }
        }
        float rn1 = rsqrtf(fmaxf(n1, 1e-12f));
        float e1w = act ? __expf(-rn1 * dkw) : 0.0f;
        float sum1w = bsum_slot(e1w, red2);
        float w1 = e1w / sum1w;
        if (act && valid){
            float buf[MSZ];
            #pragma unroll
            for (int m = 0; m < MSZ; ++m){
                float v = m1[m];
                float v2 = fmaf(-w1 * ea4[slot][1][m], v, v);
                v2 = fmaf(w1, ea4[slot][3][m], v2);
                buf[m] = v2;
            }
            float4* dst = reinterpret_cast<float4*>(outmem + (row*SS + s)*MSZ);
            #pragma unroll
            for (int q = 0; q < MSZ/4; ++q)
                dst[q] = make_float4(buf[4*q], buf[4*q+1], buf[4*q+2], buf[4*q+3]);
        }
        __syncthreads();
        if (t128 < 2*MSZ && valid){
            int hd = t128 / MSZ, m = t128 % MSZ;
            float acc = 0.0f;
            for (int s2 = 0; s2 < SS; ++s2)
                acc = fmaf(wr4[slot][hd][s2], mem0[s2*MSZ + m], acc);
            out[row*168 + 128 + hd*MSZ + m] = acc;
        }
        __syncthreads();
    }
}

extern "C" void kernel_launch(void* const* d_in, const int* in_sizes, int n_in,
                              void* d_out, int out_size, void* d_ws, size_t ws_size,
                              hipStream_t stream){
    const float* inputs = (const float*)d_in[0];
    const float* memory = (const float*)d_in[1];
    const float* Wk     = (const float*)d_in[2];
    const float* Rk     = (const float*)d_in[3];
    const float* bias   = (const float*)d_in[4];
    const float* rWk    = (const float*)d_in[5];
    const float* rbk    = (const float*)d_in[6];
    const float* wWk    = (const float*)d_in[7];
    const float* wbk    = (const float*)d_in[8];
    const float* wWe    = (const float*)d_in[9];
    const float* wbe    = (const float*)d_in[10];
    const float* wWa    = (const float*)d_in[11];
    const float* wba    = (const float*)d_in[12];

    float* out    = (float*)d_out;
    float* outmem = out + (size_t)NROW * 168;
    const size_t XW_BYTES = (size_t)NROW * FOURH * sizeof(float);   // 16.78 MB
    const int DYN_LDS = 84 * 1024;   // forces 1 block/CU (84+19.5 KB > 160/2)

    hipError_t attr_ok = hipFuncSetAttribute((const void*)k_mega,
            hipFuncAttributeMaxDynamicSharedMemorySize, DYN_LDS);

    if (attr_ok == hipSuccess && ws_size >= XW_BYTES + 256){
        // ---- path A: overlapped producer/consumer, 1 block/CU ----
        float* xw = (float*)d_ws;
        unsigned int* wm = (unsigned int*)((char*)d_ws + XW_BYTES);
        hipMemsetAsync(wm, 0, 64, stream);
        k_xw  <<<NROW/8, 512, 0, stream>>>(inputs, Wk, bias, xw);
        k_mega<<<256,    512, DYN_LDS, stream>>>(xw, Rk, memory,
                                           rWk, rbk, wWk, wbk, wWe, wbe, wWa, wba,
                                           out, outmem, wm);
    } else {
        // ---- path B: exact R9 pipeline (xw aliases outmem; ctrl in ws) ----
        float* xw   = outmem;
        float* ctrl = (float*)d_ws;
        k_xw   <<<NROW/8, 512, 0, stream>>>(inputs, Wk, bias, xw);
        k_scan <<<BB,     512, 0, stream>>>(xw, Rk, ctrl);
        k_heads<<<NROW,   128, 0, stream>>>(ctrl, memory,
                                            rWk, rbk, wWk, wbk, wWe, wbe, wWa, wba,
                                            out, outmem);
    }
}

// Round 13
// 393.578 us; speedup vs baseline: 1.2362x; 1.2290x over previous
//
#include <hip/hip_runtime.h>
#include <hip/hip_bf16.h>

#define BB 16
#define TT 512
#define DD 64
#define HH 128
#define SS 100
#define MSZ 20
#define NROW (BB*TT)      // 8192
#define FOURH 512

typedef _Float16 hf2 __attribute__((ext_vector_type(2)));   // packed half2

#if __has_builtin(__builtin_amdgcn_fdot2)
  #define FDOT2(a, b, c) __builtin_amdgcn_fdot2((a), (b), (c), false)
#else
  #define FDOT2(a, b, c) fmaf((float)(a).x, (float)(b).x, \
                          fmaf((float)(a).y, (float)(b).y, (c)))
#endif

__device__ __forceinline__ float frcp(float x){ return __builtin_amdgcn_rcpf(x); }
__device__ __forceinline__ float sigmoidf_(float x){
    return frcp(1.0f + __expf(-x));
}
__device__ __forceinline__ float tanhf_(float x){
    float t = __expf(2.0f * x);
    return 1.0f - 2.0f * frcp(t + 1.0f);   // rcp(inf)=0 -> saturates to +/-1
}

// LDS-only barrier: orders ds ops across the block WITHOUT draining vmcnt —
// global stores (ctrl) and prefetch loads (xw) stay in flight across steps.
__device__ __forceinline__ void lds_sync(){
    asm volatile("s_waitcnt lgkmcnt(0)" ::: "memory");
    __builtin_amdgcn_s_barrier();
    __builtin_amdgcn_sched_barrier(0);
}

// ---------------- kernel A: xw = inputs @ lstm_kernel + bias ----------------
// Output layout: xw[row][n*4 + g]  (gate-interleaved per neuron -> thread j of
// k_scan reads column j directly, fully coalesced).
__global__ __launch_bounds__(512) void k_xw(const float* __restrict__ inp,
        const float* __restrict__ Wk, const float* __restrict__ bias,
        float* __restrict__ xw){
    __shared__ float in_s[8 * DD];
    int tid = threadIdx.x;
    int r0 = blockIdx.x * 8;
    in_s[tid] = inp[(size_t)r0 * DD + tid];
    __syncthreads();
    int j = tid;                       // original column g*128 + n
    int n = j & 127, g = j >> 7;
    float wreg[DD];
    #pragma unroll
    for (int d = 0; d < DD; ++d) wreg[d] = Wk[d * FOURH + j];
    float bv = bias[j];
    const float4* in4 = reinterpret_cast<const float4*>(in_s);
    #pragma unroll
    for (int r = 0; r < 8; ++r){
        float acc = bv;
        #pragma unroll
        for (int q = 0; q < DD/4; ++q){
            float4 iv = in4[r*(DD/4) + q];
            acc = fmaf(iv.x, wreg[4*q+0], acc);
            acc = fmaf(iv.y, wreg[4*q+1], acc);
            acc = fmaf(iv.z, wreg[4*q+2], acc);
            acc = fmaf(iv.w, wreg[4*q+3], acc);
        }
        xw[(size_t)(r0 + r) * FOURH + n*4 + g] = acc;
    }
}

// ---------------- kernel B: LSTM scan via v_dot2_f32_f16 --------------------
// One block per batch (16 blocks). Thread j owns (neuron n=j>>2, gate g=j&3)
// and computes the FULL 128-MAC recurrent dot for that gate as 64 packed-f16
// dot2 ops (FMA-rate => 2 MAC/lane/cyc; no 16x zero-row MFMA waste, no
// reduction). The 4 gates of n live in a lane-quad: 3 shfl_xor give g==0
// lanes (i,f,g,o); other lanes compute garbage that is never written.
// h is f16 in a 256 B double-buffered LDS array, read as same-address
// broadcasts (conflict-free). One lgkmcnt-only barrier per step (R7-proven).
__global__ __launch_bounds__(512, 1) void k_scan(const float* __restrict__ xw,
        const float* __restrict__ Rk, float* __restrict__ ctrl){
    __shared__ __align__(16) _Float16 hbuf0[HH];
    __shared__ __align__(16) _Float16 hbuf1[HH];
    const int tid = threadIdx.x;
    const int b = blockIdx.x;    // batch
    const int n = tid >> 2;      // neuron 0..127
    const int g = tid & 3;       // gate 0..3 (i,f,g,o)
    const int col = g * HH + n;  // Rk column
    if (tid < HH){ hbuf0[tid] = (_Float16)0.f; hbuf1[tid] = (_Float16)0.f; }
    // ---- Rk column in registers as 64 packed half2 (64 VGPRs) ----
    hf2 rk[64];
    #pragma unroll
    for (int i = 0; i < 64; ++i){
        hf2 v;
        v.x = (_Float16)Rk[(size_t)(2*i    ) * FOURH + col];
        v.y = (_Float16)Rk[(size_t)(2*i + 1) * FOURH + col];
        rk[i] = v;
    }
    const float* xp = xw + (size_t)b * TT * FOURH + tid;   // coalesced column j
    float* cp = ctrl + (size_t)b * TT * HH + n;
    float c = 0.0f;
    float x0 = xp[0];                 // t = 0
    float x1 = xp[FOURH];             // t = 1
    union HU { uint4 u; hf2 h[4]; };
    __syncthreads();

#define DOT_STEP(HRD, HWR, XV, TOFF, TPRE, XNEW) { \
        float a0 = 0.f, a1 = 0.f, a2 = 0.f, a3 = 0.f; \
        const uint4* hr = reinterpret_cast<const uint4*>(HRD); \
        _Pragma("unroll") \
        for (int m = 0; m < 16; ++m){ \
            HU hu; hu.u = hr[m]; \
            a0 = FDOT2(hu.h[0], rk[4*m+0], a0); \
            a1 = FDOT2(hu.h[1], rk[4*m+1], a1); \
            a2 = FDOT2(hu.h[2], rk[4*m+2], a2); \
            a3 = FDOT2(hu.h[3], rk[4*m+3], a3); \
        } \
        XNEW = xp[(size_t)(TPRE) * FOURH]; \
        float z = ((a0 + a1) + (a2 + a3)) + (XV); \
        float zx1 = __shfl_xor(z, 1); \
        float zx2 = __shfl_xor(z, 2); \
        float zx3 = __shfl_xor(zx1, 2); \
        float ig = sigmoidf_(z);      /* valid on g==0 lanes */ \
        float fg = sigmoidf_(zx1); \
        float gg = tanhf_   (zx2); \
        float og = sigmoidf_(zx3); \
        c = fg * c + ig * gg; \
        float h = og * tanhf_(c); \
        if (g == 0){ \
            cp[(size_t)(TOFF) * HH] = h; \
            (HWR)[n] = (_Float16)h; \
        } \
        (XV) = XNEW; \
    }

    for (int t = 0; t < TT; t += 2){
        float xn0, xn1;
        const int tp0 = (t+2 < TT) ? t+2 : TT-1;
        const int tp1 = (t+3 < TT) ? t+3 : TT-1;
        DOT_STEP(hbuf0, hbuf1, x0, t,   tp0, xn0);
        lds_sync();
        DOT_STEP(hbuf1, hbuf0, x1, t+1, tp1, xn1);
        lds_sync();
    }
#undef DOT_STEP
}

// ---------------- kernel D: heads (proj fused), one block per (b,t) ---------
__device__ __forceinline__ float blocksum128(float v, float* red){
    #pragma unroll
    for (int o = 1; o < 64; o <<= 1) v += __shfl_xor(v, o, 64);
    int tid = threadIdx.x;
    if ((tid & 63) == 0) red[tid >> 6] = v;
    __syncthreads();
    float s = red[0] + red[1];
    __syncthreads();
    return s;
}

__global__ __launch_bounds__(128) void k_heads(const float* __restrict__ ctrl,
        const float* __restrict__ memory,
        const float* __restrict__ rWk, const float* __restrict__ rbk,
        const float* __restrict__ wWk, const float* __restrict__ wbk,
        const float* __restrict__ wWe, const float* __restrict__ wbe,
        const float* __restrict__ wWa, const float* __restrict__ wba,
        float* __restrict__ out, float* __restrict__ outmem){
    __shared__ float mem0[SS * MSZ];
    __shared__ float cs[HH];
    __shared__ float rn[SS];
    __shared__ float khat[4][MSZ];
    __shared__ float ea[4][MSZ];
    __shared__ float wrd[2][SS];
    __shared__ float red[2];
    __shared__ float pz[160];
    int tid = threadIdx.x;
    int bt = blockIdx.x;
    for (int idx = tid; idx < SS * MSZ; idx += 128) mem0[idx] = memory[idx];
    if (tid < HH){
        float v = ctrl[(size_t)bt * HH + tid];
        cs[tid] = v;
        out[(size_t)bt * 168 + tid] = v;
    }
    __syncthreads();
    if (tid < SS){
        float s2 = 0.0f;
        #pragma unroll
        for (int m = 0; m < MSZ; ++m){ float v = mem0[tid*MSZ + m]; s2 = fmaf(v, v, s2); }
        rn[tid] = rsqrtf(fmaxf(s2, 1e-12f));
    }
    for (int j = tid; j < 160; j += 128){
        int p = j / MSZ, m = j % MSZ;
        const float* Wp; const float* bp;
        switch (p){
            case 0:  Wp = rWk;            bp = rbk;        break;
            case 1:  Wp = rWk + HH*MSZ;   bp = rbk + MSZ;  break;
            case 2:  Wp = wWk;            bp = wbk;        break;
            case 3:  Wp = wWk + HH*MSZ;   bp = wbk + MSZ;  break;
            case 4:  Wp = wWe;            bp = wbe;        break;
            case 5:  Wp = wWe + HH*MSZ;   bp = wbe + MSZ;  break;
            case 6:  Wp = wWa;            bp = wba;        break;
            default: Wp = wWa + HH*MSZ;   bp = wba + MSZ;  break;
        }
        float acc = bp[m];
        const float* wcol = Wp + m;
        #pragma unroll 16
        for (int k = 0; k < HH; ++k)
            acc = fmaf(cs[k], wcol[k*MSZ], acc);
        pz[j] = acc;
    }
    __syncthreads();
    {
        int g = tid >> 5, lm = tid & 31;
        float z = (lm < MSZ) ? pz[g*MSZ + lm] : 0.0f;
        float e = (lm < MSZ) ? __expf(z) : 0.0f;
        float ssum = e;
        #pragma unroll
        for (int o = 1; o < 32; o <<= 1) ssum += __shfl_xor(ssum, o, 32);
        float kv = e / ssum;
        float qs = kv * kv;
        #pragma unroll
        for (int o = 1; o < 32; o <<= 1) qs += __shfl_xor(qs, o, 32);
        float kn = kv * rsqrtf(fmaxf(qs, 1e-12f));
        if (lm < MSZ) khat[g][lm] = kn;
        float z2 = (lm < MSZ) ? pz[80 + g*MSZ + lm] : 0.0f;
        float v2 = (g < 2) ? sigmoidf_(z2) : z2;
        if (lm < MSZ) ea[g][lm] = v2;
    }
    __syncthreads();
    bool act = tid < SS;
    int s = tid;
    float d0 = 0.f, d1 = 0.f, dw = 0.f;
    if (act){
        #pragma unroll
        for (int m = 0; m < MSZ; ++m){
            float mv = mem0[s*MSZ + m];
            d0 = fmaf(khat[0][m], mv, d0);
            d1 = fmaf(khat[1][m], mv, d1);
            dw = fmaf(khat[2][m], mv, dw);
        }
    }
    float rns = act ? rn[s] : 0.0f;
    float e0 = act ? __expf(-rns * d0) : 0.0f;
    float e1 = act ? __expf(-rns * d1) : 0.0f;
    float ew = act ? __expf(-rns * dw) : 0.0f;
    float sum0 = blocksum128(e0, red);
    float sum1 = blocksum128(e1, red);
    float sumw = blocksum128(ew, red);
    if (act){ wrd[0][s] = e0 / sum0; wrd[1][s] = e1 / sum1; }
    float w0 = ew / sumw;
    float m1[MSZ];
    float n1 = 0.f, dkw = 0.f;
    if (act){
        #pragma unroll
        for (int m = 0; m < MSZ; ++m){
            float mv = mem0[s*MSZ + m];
            float v = fmaf(-w0 * ea[0][m], mv, mv);
            v = fmaf(w0, ea[2][m], v);
            m1[m] = v;
            n1 = fmaf(v, v, n1);
            dkw = fmaf(khat[3][m], v, dkw);
        }
    }
    float rn1 = rsqrtf(fmaxf(n1, 1e-12f));
    float e1w = act ? __expf(-rn1 * dkw) : 0.0f;
    float sum1w = blocksum128(e1w, red);
    float w1 = e1w / sum1w;
    if (act){
        float buf[MSZ];
        #pragma unroll
        for (int m = 0; m < MSZ; ++m){
            float v = m1[m];
            float v2 = fmaf(-w1 * ea[1][m], v, v);
            v2 = fmaf(w1, ea[3][m], v2);
            buf[m] = v2;
        }
        float4* dst = reinterpret_cast<float4*>(outmem + ((size_t)bt * SS + s) * MSZ);
        #pragma unroll
        for (int q = 0; q < MSZ/4; ++q)
            dst[q] = make_float4(buf[4*q], buf[4*q+1], buf[4*q+2], buf[4*q+3]);
    }
    __syncthreads();
    if (tid < 2 * MSZ){
        int hd = tid / MSZ, m = tid % MSZ;
        float acc = 0.0f;
        for (int s2 = 0; s2 < SS; ++s2)
            acc = fmaf(wrd[hd][s2], mem0[s2*MSZ + m], acc);
        out[(size_t)bt * 168 + 128 + hd*MSZ + m] = acc;
    }
}

extern "C" void kernel_launch(void* const* d_in, const int* in_sizes, int n_in,
                              void* d_out, int out_size, void* d_ws, size_t ws_size,
                              hipStream_t stream){
    const float* inputs = (const float*)d_in[0];
    const float* memory = (const float*)d_in[1];
    const float* Wk     = (const float*)d_in[2];
    const float* Rk     = (const float*)d_in[3];
    const float* bias   = (const float*)d_in[4];
    const float* rWk    = (const float*)d_in[5];
    const float* rbk    = (const float*)d_in[6];
    const float* wWk    = (const float*)d_in[7];
    const float* wbk    = (const float*)d_in[8];
    const float* wWe    = (const float*)d_in[9];
    const float* wbe    = (const float*)d_in[10];
    const float* wWa    = (const float*)d_in[11];
    const float* wba    = (const float*)d_in[12];

    float* out    = (float*)d_out;
    float* outmem = out + (size_t)NROW * 168;
    // xw scratch aliases the (dead until k_heads) mem-output region
    float* xw   = outmem;
    float* ctrl = (float*)d_ws;

    k_xw   <<<NROW/8, 512, 0, stream>>>(inputs, Wk, bias, xw);
    k_scan <<<BB,     512, 0, stream>>>(xw, Rk, ctrl);
    k_heads<<<NROW,   128, 0, stream>>>(ctrl, memory,
                                        rWk, rbk, wWk, wbk, wWe, wbe, wWa, wba,
                                        out, outmem);
}

// Round 14
// 310.855 us; speedup vs baseline: 1.5651x; 1.2661x over previous
//
#include <hip/hip_runtime.h>
#include <hip/hip_bf16.h>

#define BB 16
#define TT 512
#define DD 64
#define HH 128
#define SS 100
#define MSZ 20
#define NROW (BB*TT)      // 8192
#define FOURH 512

typedef __attribute__((ext_vector_type(8))) short bh8;   // 8 bf16 in 4 VGPRs
typedef __attribute__((ext_vector_type(4))) float fv4;   // MFMA accumulator

__device__ __forceinline__ float frcp(float x){ return __builtin_amdgcn_rcpf(x); }
__device__ __forceinline__ float sigmoidf_(float x){
    return frcp(1.0f + __expf(-x));
}
__device__ __forceinline__ float tanhf_(float x){
    float t = __expf(2.0f * x);
    return 1.0f - 2.0f * frcp(t + 1.0f);   // rcp(inf)=0 -> saturates to +/-1
}
__device__ __forceinline__ unsigned short f2bf(float f){
    __hip_bfloat16 h = __float2bfloat16(f);   // RNE
    union { __hip_bfloat16 b; unsigned short u; } cv; cv.b = h;
    return cv.u;
}

// LDS-only barrier: orders ds ops across the block WITHOUT draining vmcnt —
// global stores (ctrl) and prefetch loads (xw) stay in flight across steps.
__device__ __forceinline__ void lds_sync(){
    asm volatile("s_waitcnt lgkmcnt(0)" ::: "memory");
    __builtin_amdgcn_s_barrier();
    __builtin_amdgcn_sched_barrier(0);
}

// ---------------- kernel A: xw = inputs @ lstm_kernel + bias ----------------
// Output layout: xw[row][n*4 + g]  (gate-interleaved per neuron -> float4/step
// loads in k_scan). row = b*TT + t, n = 0..127, g = i,f,g,o.
__global__ __launch_bounds__(512) void k_xw(const float* __restrict__ inp,
        const float* __restrict__ Wk, const float* __restrict__ bias,
        float* __restrict__ xw){
    __shared__ float in_s[8 * DD];
    int tid = threadIdx.x;
    int r0 = blockIdx.x * 8;
    in_s[tid] = inp[(size_t)r0 * DD + tid];
    __syncthreads();
    int j = tid;                       // original column g*128 + n
    int n = j & 127, g = j >> 7;
    float wreg[DD];
    #pragma unroll
    for (int d = 0; d < DD; ++d) wreg[d] = Wk[d * FOURH + j];
    float bv = bias[j];
    const float4* in4 = reinterpret_cast<const float4*>(in_s);
    #pragma unroll
    for (int r = 0; r < 8; ++r){
        float acc = bv;
        #pragma unroll
        for (int q = 0; q < DD/4; ++q){
            float4 iv = in4[r*(DD/4) + q];
            acc = fmaf(iv.x, wreg[4*q+0], acc);
            acc = fmaf(iv.y, wreg[4*q+1], acc);
            acc = fmaf(iv.z, wreg[4*q+2], acc);
            acc = fmaf(iv.w, wreg[4*q+3], acc);
        }
        xw[(size_t)(r0 + r) * FOURH + n*4 + g] = acc;
    }
}

// ---------------- kernel B: LSTM scan via MFMA (R7, proven) -----------------
__global__ __launch_bounds__(512, 2) void k_scan(const float* __restrict__ xw,
        const float* __restrict__ Rk, float* __restrict__ ctrl){
    __shared__ __align__(16) unsigned short hbuf0[HH];
    __shared__ __align__(16) unsigned short hbuf1[HH];
    const int tid = threadIdx.x;
    const int b  = blockIdx.x;   // batch
    const int w  = tid >> 6;     // wave 0..7
    const int l  = tid & 63;
    const int q  = l >> 4;       // k-group 0..3
    const int lo = l & 15;       // A-row / C-col
    if (tid < HH){ hbuf0[tid] = 0; hbuf1[tid] = 0; }
    // ---- Rk B-fragments (bf16), resident in VGPRs: 64 VGPRs ----
    bh8 bf[4][4];
    #pragma unroll
    for (int Ti = 0; Ti < 4; ++Ti){
        const int col = Ti*128 + w*16 + lo;
        #pragma unroll
        for (int kk = 0; kk < 4; ++kk){
            union { unsigned short us[8]; bh8 v; } u;
            #pragma unroll
            for (int j = 0; j < 8; ++j)
                u.us[j] = f2bf(Rk[(size_t)(kk*32 + q*8 + j)*FOURH + col]);
            bf[Ti][kk] = u.v;
        }
    }
    const bool upd = (q == 0);          // lanes 0..15: own neuron n = 16w+lo
    const bool rdh = (lo == 0);         // lanes 0,16,32,48: carry real A data
    const int  n   = w*16 + lo;
    const float4* xb4 = reinterpret_cast<const float4*>(xw) + (size_t)b*TT*HH + n;
    float* cptr = ctrl + (size_t)b*TT*HH + n;
    float c0 = 0.0f;
    float4 x0 = {0,0,0,0}, x1 = {0,0,0,0}, xp0 = {0,0,0,0}, xp1 = {0,0,0,0};
    if (upd){ x0 = xb4[0]; x1 = xb4[(size_t)HH]; }
    union AU { uint4 u; bh8 v; };
    AU a0, a1, a2, a3;                   // zero-init ONCE; only rdh lanes ever written
    a0.u = make_uint4(0u,0u,0u,0u); a1.u = a0.u; a2.u = a0.u; a3.u = a0.u;
    const fv4 zz = {0.f, 0.f, 0.f, 0.f};
    __syncthreads();

#define MFMA16() \
        fv4 z0 = __builtin_amdgcn_mfma_f32_16x16x32_bf16(a0.v, bf[0][0], zz, 0,0,0); \
        fv4 z1 = __builtin_amdgcn_mfma_f32_16x16x32_bf16(a0.v, bf[1][0], zz, 0,0,0); \
        fv4 z2 = __builtin_amdgcn_mfma_f32_16x16x32_bf16(a0.v, bf[2][0], zz, 0,0,0); \
        fv4 z3 = __builtin_amdgcn_mfma_f32_16x16x32_bf16(a0.v, bf[3][0], zz, 0,0,0); \
        z0 = __builtin_amdgcn_mfma_f32_16x16x32_bf16(a1.v, bf[0][1], z0, 0,0,0); \
        z1 = __builtin_amdgcn_mfma_f32_16x16x32_bf16(a1.v, bf[1][1], z1, 0,0,0); \
        z2 = __builtin_amdgcn_mfma_f32_16x16x32_bf16(a1.v, bf[2][1], z2, 0,0,0); \
        z3 = __builtin_amdgcn_mfma_f32_16x16x32_bf16(a1.v, bf[3][1], z3, 0,0,0); \
        z0 = __builtin_amdgcn_mfma_f32_16x16x32_bf16(a2.v, bf[0][2], z0, 0,0,0); \
        z1 = __builtin_amdgcn_mfma_f32_16x16x32_bf16(a2.v, bf[1][2], z1, 0,0,0); \
        z2 = __builtin_amdgcn_mfma_f32_16x16x32_bf16(a2.v, bf[2][2], z2, 0,0,0); \
        z3 = __builtin_amdgcn_mfma_f32_16x16x32_bf16(a2.v, bf[3][2], z3, 0,0,0); \
        z0 = __builtin_amdgcn_mfma_f32_16x16x32_bf16(a3.v, bf[0][3], z0, 0,0,0); \
        z1 = __builtin_amdgcn_mfma_f32_16x16x32_bf16(a3.v, bf[1][3], z1, 0,0,0); \
        z2 = __builtin_amdgcn_mfma_f32_16x16x32_bf16(a3.v, bf[2][3], z2, 0,0,0); \
        z3 = __builtin_amdgcn_mfma_f32_16x16x32_bf16(a3.v, bf[3][3], z3, 0,0,0);

    for (int t = 0; t < TT; t += 2){
        // ---------- substep A: time t; read hbuf0, write hbuf1 ----------
        if (rdh){
            const uint4* hr = reinterpret_cast<const uint4*>(hbuf0);
            a0.u = hr[q]; a1.u = hr[q+4]; a2.u = hr[q+8]; a3.u = hr[q+12];
        }
        {
            const int tn = (t+2 < TT) ? t+2 : TT-1;
            if (upd) xp0 = xb4[(size_t)tn * HH];
        }
        {
            MFMA16();
            if (upd){
                float ig = sigmoidf_(z0[0] + x0.x);
                float fg = sigmoidf_(z1[0] + x0.y);
                float gg = tanhf_   (z2[0] + x0.z);
                float og = sigmoidf_(z3[0] + x0.w);
                c0 = fg * c0 + ig * gg;
                float h = og * tanhf_(c0);
                cptr[(size_t)t * HH] = h;
                hbuf1[n] = f2bf(h);
            }
        }
        lds_sync();
        // ---------- substep B: time t+1; read hbuf1, write hbuf0 ----------
        if (rdh){
            const uint4* hr = reinterpret_cast<const uint4*>(hbuf1);
            a0.u = hr[q]; a1.u = hr[q+4]; a2.u = hr[q+8]; a3.u = hr[q+12];
        }
        {
            const int tn = (t+3 < TT) ? t+3 : TT-1;
            if (upd) xp1 = xb4[(size_t)tn * HH];
        }
        {
            MFMA16();
            if (upd){
                float ig = sigmoidf_(z0[0] + x1.x);
                float fg = sigmoidf_(z1[0] + x1.y);
                float gg = tanhf_   (z2[0] + x1.z);
                float og = sigmoidf_(z3[0] + x1.w);
                c0 = fg * c0 + ig * gg;
                float h = og * tanhf_(c0);
                cptr[(size_t)(t+1) * HH] = h;
                hbuf0[n] = f2bf(h);
            }
        }
        x0 = xp0; x1 = xp1;
        lds_sync();
    }
#undef MFMA16
}

// ---------------- kernel D: heads x4 per block (512 threads) ----------------
// 4 head-items per block: weights (80 KB) and mem0 (8 KB) traffic through L2
// amortize 4x, and 8 waves/block hide the L2-latency-bound proj loads. The
// 4-slot structure is the R10/R11 consumer body (correctness-proven) minus
// the watermark handshake. slot = tid>>7 owns item blockIdx.x*4 + slot.
__device__ __forceinline__ float bsum_slot(float v, float* red2){
    #pragma unroll
    for (int o = 1; o < 64; o <<= 1) v += __shfl_xor(v, o, 64);
    int tid = threadIdx.x;
    if ((tid & 63) == 0) red2[(tid >> 6) & 1] = v;
    __syncthreads();
    float s = red2[0] + red2[1];
    __syncthreads();
    return s;
}

__global__ __launch_bounds__(512) void k_heads4(const float* __restrict__ ctrl,
        const float* __restrict__ memory,
        const float* __restrict__ rWk, const float* __restrict__ rbk,
        const float* __restrict__ wWk, const float* __restrict__ wbk,
        const float* __restrict__ wWe, const float* __restrict__ wbe,
        const float* __restrict__ wWa, const float* __restrict__ wba,
        float* __restrict__ out, float* __restrict__ outmem){
    __shared__ float mem0[SS * MSZ];
    __shared__ float rn_s[SS];
    __shared__ float cs4[4][HH];
    __shared__ float pz4[4][160];
    __shared__ float kh4[4][4][MSZ];
    __shared__ float ea4[4][4][MSZ];
    __shared__ float wr4[4][2][SS];
    __shared__ float rd4[4][2];
    const int tid  = threadIdx.x;
    const int t128 = tid & 127;
    const int slot = tid >> 7;
    const size_t row = (size_t)blockIdx.x * 4 + slot;   // bt index 0..8191
    float* red2 = rd4[slot];
    for (int idx = tid; idx < SS * MSZ; idx += 512) mem0[idx] = memory[idx];
    // ctrl row -> LDS + out[:,0:128] copy
    {
        float v = ctrl[row * HH + t128];
        cs4[slot][t128] = v;
        out[row * 168 + t128] = v;
    }
    __syncthreads();
    if (tid < SS){
        float s2 = 0.0f;
        #pragma unroll
        for (int m = 0; m < MSZ; ++m){ float v = mem0[tid*MSZ + m]; s2 = fmaf(v, v, s2); }
        rn_s[tid] = rsqrtf(fmaxf(s2, 1e-12f));
    }
    __syncthreads();
    // ---- fused proj: pz[j] = ctrl_row . W[:,j] + b  (j = 0..159) ----
    for (int j = t128; j < 160; j += 128){
        int p = j / MSZ, m = j % MSZ;
        const float* Wp; const float* bp;
        switch (p){
            case 0:  Wp = rWk;            bp = rbk;        break;
            case 1:  Wp = rWk + HH*MSZ;   bp = rbk + MSZ;  break;
            case 2:  Wp = wWk;            bp = wbk;        break;
            case 3:  Wp = wWk + HH*MSZ;   bp = wbk + MSZ;  break;
            case 4:  Wp = wWe;            bp = wbe;        break;
            case 5:  Wp = wWe + HH*MSZ;   bp = wbe + MSZ;  break;
            case 6:  Wp = wWa;            bp = wba;        break;
            default: Wp = wWa + HH*MSZ;   bp = wba + MSZ;  break;
        }
        float acc = bp[m];
        const float* wcol = Wp + m;
        #pragma unroll 16
        for (int k = 0; k < HH; ++k)
            acc = fmaf(cs4[slot][k], wcol[k*MSZ], acc);   // LDS broadcast
        pz4[slot][j] = acc;
    }
    __syncthreads();
    {   // 4 key heads: softmax over 20 then l2-normalize; plus e/a heads
        int g = t128 >> 5, lm = t128 & 31;
        float z = (lm < MSZ) ? pz4[slot][g*MSZ + lm] : 0.0f;
        float e = (lm < MSZ) ? __expf(z) : 0.0f;
        float ssum = e;
        #pragma unroll
        for (int o = 1; o < 32; o <<= 1) ssum += __shfl_xor(ssum, o, 32);
        float kv = e / ssum;
        float qs = kv * kv;
        #pragma unroll
        for (int o = 1; o < 32; o <<= 1) qs += __shfl_xor(qs, o, 32);
        float kn = kv * rsqrtf(fmaxf(qs, 1e-12f));
        if (lm < MSZ) kh4[slot][g][lm] = kn;
        float z2 = (lm < MSZ) ? pz4[slot][80 + g*MSZ + lm] : 0.0f;
        float v2 = (g < 2) ? sigmoidf_(z2) : z2;
        if (lm < MSZ) ea4[slot][g][lm] = v2;
    }
    __syncthreads();
    bool act = t128 < SS;
    int s = t128;
    float d0 = 0.f, d1 = 0.f, dw = 0.f;
    if (act){
        #pragma unroll
        for (int m = 0; m < MSZ; ++m){
            float mv = mem0[s*MSZ + m];
            d0 = fmaf(kh4[slot][0][m], mv, d0);
            d1 = fmaf(kh4[slot][1][m], mv, d1);
            dw = fmaf(kh4[slot][2][m], mv, dw);
        }
    }
    float rns = act ? rn_s[s] : 0.0f;
    float e0 = act ? __expf(-rns * d0) : 0.0f;
    float e1 = act ? __expf(-rns * d1) : 0.0f;
    float ew = act ? __expf(-rns * dw) : 0.0f;
    float sum0 = bsum_slot(e0, red2);
    float sum1 = bsum_slot(e1, red2);
    float sumw = bsum_slot(ew, red2);
    if (act){ wr4[slot][0][s] = e0 / sum0; wr4[slot][1][s] = e1 / sum1; }
    float w0 = ew / sumw;
    float m1[MSZ];
    float n1 = 0.f, dkw = 0.f;
    if (act){
        #pragma unroll
        for (int m = 0; m < MSZ; ++m){
            float mv = mem0[s*MSZ + m];
            float v = fmaf(-w0 * ea4[slot][0][m], mv, mv);   // (1 - w0*e0)*mem
            v = fmaf(w0, ea4[slot][2][m], v);                // + w0*a0
            m1[m] = v;
            n1 = fmaf(v, v, n1);
            dkw = fmaf(kh4[slot][3][m], v, dkw);
        }
    }
    float rn1 = rsqrtf(fmaxf(n1, 1e-12f));
    float e1w = act ? __expf(-rn1 * dkw) : 0.0f;
    float sum1w = bsum_slot(e1w, red2);
    float w1 = e1w / sum1w;
    if (act){
        float buf[MSZ];
        #pragma unroll
        for (int m = 0; m < MSZ; ++m){
            float v = m1[m];
            float v2 = fmaf(-w1 * ea4[slot][1][m], v, v);
            v2 = fmaf(w1, ea4[slot][3][m], v2);
            buf[m] = v2;
        }
        float4* dst = reinterpret_cast<float4*>(outmem + (row*SS + s)*MSZ);
        #pragma unroll
        for (int q = 0; q < MSZ/4; ++q)
            dst[q] = make_float4(buf[4*q], buf[4*q+1], buf[4*q+2], buf[4*q+3]);
    }
    __syncthreads();
    if (t128 < 2*MSZ){
        int hd = t128 / MSZ, m = t128 % MSZ;
        float acc = 0.0f;
        for (int s2 = 0; s2 < SS; ++s2)
            acc = fmaf(wr4[slot][hd][s2], mem0[s2*MSZ + m], acc);
        out[row*168 + 128 + hd*MSZ + m] = acc;
    }
}

extern "C" void kernel_launch(void* const* d_in, const int* in_sizes, int n_in,
                              void* d_out, int out_size, void* d_ws, size_t ws_size,
                              hipStream_t stream){
    const float* inputs = (const float*)d_in[0];
    const float* memory = (const float*)d_in[1];
    const float* Wk     = (const float*)d_in[2];
    const float* Rk     = (const float*)d_in[3];
    const float* bias   = (const float*)d_in[4];
    const float* rWk    = (const float*)d_in[5];
    const float* rbk    = (const float*)d_in[6];
    const float* wWk    = (const float*)d_in[7];
    const float* wbk    = (const float*)d_in[8];
    const float* wWe    = (const float*)d_in[9];
    const float* wbe    = (const float*)d_in[10];
    const float* wWa    = (const float*)d_in[11];
    const float* wba    = (const float*)d_in[12];

    float* out    = (float*)d_out;
    float* outmem = out + (size_t)NROW * 168;
    // xw scratch aliases the (dead until k_heads4) mem-output region
    float* xw   = outmem;
    float* ctrl = (float*)d_ws;

    k_xw    <<<NROW/8, 512, 0, stream>>>(inputs, Wk, bias, xw);
    k_scan  <<<BB,     512, 0, stream>>>(xw, Rk, ctrl);
    k_heads4<<<NROW/4, 512, 0, stream>>>(ctrl, memory,
                                         rWk, rbk, wWk, wbk, wWe, wbe, wWa, wba,
                                         out, outmem);
}

// Round 15
// 308.000 us; speedup vs baseline: 1.5797x; 1.0093x over previous
//
#include <hip/hip_runtime.h>
#include <hip/hip_bf16.h>

#define BB 16
#define TT 512
#define DD 64
#define HH 128
#define SS 100
#define MSZ 20
#define NROW (BB*TT)      // 8192
#define FOURH 512

typedef __attribute__((ext_vector_type(8))) short bh8;   // 8 bf16 in 4 VGPRs
typedef __attribute__((ext_vector_type(4))) float fv4;   // MFMA accumulator

__device__ __forceinline__ float frcp(float x){ return __builtin_amdgcn_rcpf(x); }
__device__ __forceinline__ float sigmoidf_(float x){
    return frcp(1.0f + __expf(-x));
}
__device__ __forceinline__ float tanhf_(float x){
    float t = __expf(2.0f * x);
    return 1.0f - 2.0f * frcp(t + 1.0f);   // rcp(inf)=0 -> saturates to +/-1
}
__device__ __forceinline__ unsigned short f2bf(float f){
    __hip_bfloat16 h = __float2bfloat16(f);   // RNE
    union { __hip_bfloat16 b; unsigned short u; } cv; cv.b = h;
    return cv.u;
}

// LDS-only barrier: orders ds ops across the block WITHOUT draining vmcnt —
// global stores (ctrl) and prefetch loads (xw) stay in flight across steps.
__device__ __forceinline__ void lds_sync(){
    asm volatile("s_waitcnt lgkmcnt(0)" ::: "memory");
    __builtin_amdgcn_s_barrier();
    __builtin_amdgcn_sched_barrier(0);
}

// ---------------- kernel A: xw = inputs @ lstm_kernel + bias ----------------
// Output layout: xw[row][n*4 + g]  (gate-interleaved per neuron -> float4/step
// loads in k_scan). row = b*TT + t, n = 0..127, g = i,f,g,o.
__global__ __launch_bounds__(512) void k_xw(const float* __restrict__ inp,
        const float* __restrict__ Wk, const float* __restrict__ bias,
        float* __restrict__ xw){
    __shared__ float in_s[8 * DD];
    int tid = threadIdx.x;
    int r0 = blockIdx.x * 8;
    in_s[tid] = inp[(size_t)r0 * DD + tid];
    __syncthreads();
    int j = tid;                       // original column g*128 + n
    int n = j & 127, g = j >> 7;
    float wreg[DD];
    #pragma unroll
    for (int d = 0; d < DD; ++d) wreg[d] = Wk[d * FOURH + j];
    float bv = bias[j];
    const float4* in4 = reinterpret_cast<const float4*>(in_s);
    #pragma unroll
    for (int r = 0; r < 8; ++r){
        float acc = bv;
        #pragma unroll
        for (int q = 0; q < DD/4; ++q){
            float4 iv = in4[r*(DD/4) + q];
            acc = fmaf(iv.x, wreg[4*q+0], acc);
            acc = fmaf(iv.y, wreg[4*q+1], acc);
            acc = fmaf(iv.z, wreg[4*q+2], acc);
            acc = fmaf(iv.w, wreg[4*q+3], acc);
        }
        xw[(size_t)(r0 + r) * FOURH + n*4 + g] = acc;
    }
}

// ---------------- kernel B: LSTM scan via MFMA (R7, proven) -----------------
__global__ __launch_bounds__(512, 2) void k_scan(const float* __restrict__ xw,
        const float* __restrict__ Rk, float* __restrict__ ctrl){
    __shared__ __align__(16) unsigned short hbuf0[HH];
    __shared__ __align__(16) unsigned short hbuf1[HH];
    const int tid = threadIdx.x;
    const int b  = blockIdx.x;   // batch
    const int w  = tid >> 6;     // wave 0..7
    const int l  = tid & 63;
    const int q  = l >> 4;       // k-group 0..3
    const int lo = l & 15;       // A-row / C-col
    if (tid < HH){ hbuf0[tid] = 0; hbuf1[tid] = 0; }
    // ---- Rk B-fragments (bf16), resident in VGPRs: 64 VGPRs ----
    bh8 bf[4][4];
    #pragma unroll
    for (int Ti = 0; Ti < 4; ++Ti){
        const int col = Ti*128 + w*16 + lo;
        #pragma unroll
        for (int kk = 0; kk < 4; ++kk){
            union { unsigned short us[8]; bh8 v; } u;
            #pragma unroll
            for (int j = 0; j < 8; ++j)
                u.us[j] = f2bf(Rk[(size_t)(kk*32 + q*8 + j)*FOURH + col]);
            bf[Ti][kk] = u.v;
        }
    }
    const bool upd = (q == 0);          // lanes 0..15: own neuron n = 16w+lo
    const bool rdh = (lo == 0);         // lanes 0,16,32,48: carry real A data
    const int  n   = w*16 + lo;
    const float4* xb4 = reinterpret_cast<const float4*>(xw) + (size_t)b*TT*HH + n;
    float* cptr = ctrl + (size_t)b*TT*HH + n;
    float c0 = 0.0f;
    float4 x0 = {0,0,0,0}, x1 = {0,0,0,0}, xp0 = {0,0,0,0}, xp1 = {0,0,0,0};
    if (upd){ x0 = xb4[0]; x1 = xb4[(size_t)HH]; }
    union AU { uint4 u; bh8 v; };
    AU a0, a1, a2, a3;                   // zero-init ONCE; only rdh lanes ever written
    a0.u = make_uint4(0u,0u,0u,0u); a1.u = a0.u; a2.u = a0.u; a3.u = a0.u;
    const fv4 zz = {0.f, 0.f, 0.f, 0.f};
    __syncthreads();

#define MFMA16() \
        fv4 z0 = __builtin_amdgcn_mfma_f32_16x16x32_bf16(a0.v, bf[0][0], zz, 0,0,0); \
        fv4 z1 = __builtin_amdgcn_mfma_f32_16x16x32_bf16(a0.v, bf[1][0], zz, 0,0,0); \
        fv4 z2 = __builtin_amdgcn_mfma_f32_16x16x32_bf16(a0.v, bf[2][0], zz, 0,0,0); \
        fv4 z3 = __builtin_amdgcn_mfma_f32_16x16x32_bf16(a0.v, bf[3][0], zz, 0,0,0); \
        z0 = __builtin_amdgcn_mfma_f32_16x16x32_bf16(a1.v, bf[0][1], z0, 0,0,0); \
        z1 = __builtin_amdgcn_mfma_f32_16x16x32_bf16(a1.v, bf[1][1], z1, 0,0,0); \
        z2 = __builtin_amdgcn_mfma_f32_16x16x32_bf16(a1.v, bf[2][1], z2, 0,0,0); \
        z3 = __builtin_amdgcn_mfma_f32_16x16x32_bf16(a1.v, bf[3][1], z3, 0,0,0); \
        z0 = __builtin_amdgcn_mfma_f32_16x16x32_bf16(a2.v, bf[0][2], z0, 0,0,0); \
        z1 = __builtin_amdgcn_mfma_f32_16x16x32_bf16(a2.v, bf[1][2], z1, 0,0,0); \
        z2 = __builtin_amdgcn_mfma_f32_16x16x32_bf16(a2.v, bf[2][2], z2, 0,0,0); \
        z3 = __builtin_amdgcn_mfma_f32_16x16x32_bf16(a2.v, bf[3][2], z3, 0,0,0); \
        z0 = __builtin_amdgcn_mfma_f32_16x16x32_bf16(a3.v, bf[0][3], z0, 0,0,0); \
        z1 = __builtin_amdgcn_mfma_f32_16x16x32_bf16(a3.v, bf[1][3], z1, 0,0,0); \
        z2 = __builtin_amdgcn_mfma_f32_16x16x32_bf16(a3.v, bf[2][3], z2, 0,0,0); \
        z3 = __builtin_amdgcn_mfma_f32_16x16x32_bf16(a3.v, bf[3][3], z3, 0,0,0);

    for (int t = 0; t < TT; t += 2){
        // ---------- substep A: time t; read hbuf0, write hbuf1 ----------
        if (rdh){
            const uint4* hr = reinterpret_cast<const uint4*>(hbuf0);
            a0.u = hr[q]; a1.u = hr[q+4]; a2.u = hr[q+8]; a3.u = hr[q+12];
        }
        {
            const int tn = (t+2 < TT) ? t+2 : TT-1;
            if (upd) xp0 = xb4[(size_t)tn * HH];
        }
        {
            MFMA16();
            if (upd){
                float ig = sigmoidf_(z0[0] + x0.x);
                float fg = sigmoidf_(z1[0] + x0.y);
                float gg = tanhf_   (z2[0] + x0.z);
                float og = sigmoidf_(z3[0] + x0.w);
                c0 = fg * c0 + ig * gg;
                float h = og * tanhf_(c0);
                cptr[(size_t)t * HH] = h;
                hbuf1[n] = f2bf(h);
            }
        }
        lds_sync();
        // ---------- substep B: time t+1; read hbuf1, write hbuf0 ----------
        if (rdh){
            const uint4* hr = reinterpret_cast<const uint4*>(hbuf1);
            a0.u = hr[q]; a1.u = hr[q+4]; a2.u = hr[q+8]; a3.u = hr[q+12];
        }
        {
            const int tn = (t+3 < TT) ? t+3 : TT-1;
            if (upd) xp1 = xb4[(size_t)tn * HH];
        }
        {
            MFMA16();
            if (upd){
                float ig = sigmoidf_(z0[0] + x1.x);
                float fg = sigmoidf_(z1[0] + x1.y);
                float gg = tanhf_   (z2[0] + x1.z);
                float og = sigmoidf_(z3[0] + x1.w);
                c0 = fg * c0 + ig * gg;
                float h = og * tanhf_(c0);
                cptr[(size_t)(t+1) * HH] = h;
                hbuf0[n] = f2bf(h);
            }
        }
        x0 = xp0; x1 = xp1;
        lds_sync();
    }
#undef MFMA16
}

// ---------------- kernel D: heads (proj fused), 4 items SEQUENTIALLY --------
// R9's proven 128-thread per-item body wrapped in a 4-item loop. mem0 staging
// and the rn norm phase are item-invariant -> hoisted out (saves 3/4 of the
// stage phases, 50 MB L2 traffic, and 2 barriers x 3 items per block). 2048
// blocks = 8/CU all co-resident in ONE dispatch wave.
__device__ __forceinline__ float blocksum128(float v, float* red){
    #pragma unroll
    for (int o = 1; o < 64; o <<= 1) v += __shfl_xor(v, o, 64);
    int tid = threadIdx.x;
    if ((tid & 63) == 0) red[tid >> 6] = v;
    __syncthreads();
    float s = red[0] + red[1];
    __syncthreads();
    return s;
}

__global__ __launch_bounds__(128) void k_heads(const float* __restrict__ ctrl,
        const float* __restrict__ memory,
        const float* __restrict__ rWk, const float* __restrict__ rbk,
        const float* __restrict__ wWk, const float* __restrict__ wbk,
        const float* __restrict__ wWe, const float* __restrict__ wbe,
        const float* __restrict__ wWa, const float* __restrict__ wba,
        float* __restrict__ out, float* __restrict__ outmem){
    __shared__ float mem0[SS * MSZ];
    __shared__ float cs[HH];
    __shared__ float rn[SS];
    __shared__ float khat[4][MSZ];
    __shared__ float ea[4][MSZ];
    __shared__ float wrd[2][SS];
    __shared__ float red[2];
    __shared__ float pz[160];
    const int tid = threadIdx.x;
    // ---- item-invariant staging (once per block) ----
    for (int idx = tid; idx < SS * MSZ; idx += 128) mem0[idx] = memory[idx];
    __syncthreads();
    if (tid < SS){
        float s2 = 0.0f;
        #pragma unroll
        for (int m = 0; m < MSZ; ++m){ float v = mem0[tid*MSZ + m]; s2 = fmaf(v, v, s2); }
        rn[tid] = rsqrtf(fmaxf(s2, 1e-12f));
    }
    __syncthreads();

    for (int it = 0; it < 4; ++it){
        const size_t bt = (size_t)blockIdx.x * 4 + it;
        if (tid < HH){
            float v = ctrl[bt * HH + tid];
            cs[tid] = v;
            out[bt * 168 + tid] = v;   // ctrl copy into out[:,0:128]
        }
        __syncthreads();
        // ---- fused proj: pz[j] = ctrl_row . W[:,j] + b  (j = 0..159) ----
        for (int j = tid; j < 160; j += 128){
            int p = j / MSZ, m = j % MSZ;
            const float* Wp; const float* bp;
            switch (p){
                case 0:  Wp = rWk;            bp = rbk;        break;
                case 1:  Wp = rWk + HH*MSZ;   bp = rbk + MSZ;  break;
                case 2:  Wp = wWk;            bp = wbk;        break;
                case 3:  Wp = wWk + HH*MSZ;   bp = wbk + MSZ;  break;
                case 4:  Wp = wWe;            bp = wbe;        break;
                case 5:  Wp = wWe + HH*MSZ;   bp = wbe + MSZ;  break;
                case 6:  Wp = wWa;            bp = wba;        break;
                default: Wp = wWa + HH*MSZ;   bp = wba + MSZ;  break;
            }
            float acc = bp[m];
            const float* wcol = Wp + m;
            #pragma unroll 16
            for (int k = 0; k < HH; ++k)
                acc = fmaf(cs[k], wcol[k*MSZ], acc);   // cs[k]: LDS broadcast
            pz[j] = acc;
        }
        __syncthreads();
        {   // 4 key heads: softmax over 20 then l2-normalize; plus e/a heads
            int g = tid >> 5, lm = tid & 31;
            float z = (lm < MSZ) ? pz[g*MSZ + lm] : 0.0f;
            float e = (lm < MSZ) ? __expf(z) : 0.0f;
            float ssum = e;
            #pragma unroll
            for (int o = 1; o < 32; o <<= 1) ssum += __shfl_xor(ssum, o, 32);
            float kv = e / ssum;
            float qs = kv * kv;
            #pragma unroll
            for (int o = 1; o < 32; o <<= 1) qs += __shfl_xor(qs, o, 32);
            float kn = kv * rsqrtf(fmaxf(qs, 1e-12f));
            if (lm < MSZ) khat[g][lm] = kn;
            float z2 = (lm < MSZ) ? pz[80 + g*MSZ + lm] : 0.0f;
            float v2 = (g < 2) ? sigmoidf_(z2) : z2;
            if (lm < MSZ) ea[g][lm] = v2;
        }
        __syncthreads();
        bool act = tid < SS;
        int s = tid;
        float d0 = 0.f, d1 = 0.f, dw = 0.f;
        if (act){
            #pragma unroll
            for (int m = 0; m < MSZ; ++m){
                float mv = mem0[s*MSZ + m];
                d0 = fmaf(khat[0][m], mv, d0);
                d1 = fmaf(khat[1][m], mv, d1);
                dw = fmaf(khat[2][m], mv, dw);
            }
        }
        float rns = act ? rn[s] : 0.0f;
        float e0 = act ? __expf(-rns * d0) : 0.0f;
        float e1 = act ? __expf(-rns * d1) : 0.0f;
        float ew = act ? __expf(-rns * dw) : 0.0f;
        float sum0 = blocksum128(e0, red);
        float sum1 = blocksum128(e1, red);
        float sumw = blocksum128(ew, red);
        if (act){ wrd[0][s] = e0 / sum0; wrd[1][s] = e1 / sum1; }
        float w0 = ew / sumw;
        float m1[MSZ];
        float n1 = 0.f, dkw = 0.f;
        if (act){
            #pragma unroll
            for (int m = 0; m < MSZ; ++m){
                float mv = mem0[s*MSZ + m];
                float v = fmaf(-w0 * ea[0][m], mv, mv);   // (1 - w0*e0)*mem
                v = fmaf(w0, ea[2][m], v);                // + w0*a0
                m1[m] = v;
                n1 = fmaf(v, v, n1);
                dkw = fmaf(khat[3][m], v, dkw);
            }
        }
        float rn1 = rsqrtf(fmaxf(n1, 1e-12f));
        float e1w = act ? __expf(-rn1 * dkw) : 0.0f;
        float sum1w = blocksum128(e1w, red);
        float w1 = e1w / sum1w;
        if (act){
            float buf[MSZ];
            #pragma unroll
            for (int m = 0; m < MSZ; ++m){
                float v = m1[m];
                float v2 = fmaf(-w1 * ea[1][m], v, v);
                v2 = fmaf(w1, ea[3][m], v2);
                buf[m] = v2;
            }
            float4* dst = reinterpret_cast<float4*>(outmem + (bt * SS + s) * MSZ);
            #pragma unroll
            for (int q = 0; q < MSZ/4; ++q)
                dst[q] = make_float4(buf[4*q], buf[4*q+1], buf[4*q+2], buf[4*q+3]);
        }
        __syncthreads();
        if (tid < 2 * MSZ){
            int hd = tid / MSZ, m = tid % MSZ;
            float acc = 0.0f;
            for (int s2 = 0; s2 < SS; ++s2)
                acc = fmaf(wrd[hd][s2], mem0[s2*MSZ + m], acc);
            out[bt * 168 + 128 + hd*MSZ + m] = acc;
        }
        __syncthreads();   // protect khat/ea/wrd/cs/pz before next item
    }
}

extern "C" void kernel_launch(void* const* d_in, const int* in_sizes, int n_in,
                              void* d_out, int out_size, void* d_ws, size_t ws_size,
                              hipStream_t stream){
    const float* inputs = (const float*)d_in[0];
    const float* memory = (const float*)d_in[1];
    const float* Wk     = (const float*)d_in[2];
    const float* Rk     = (const float*)d_in[3];
    const float* bias   = (const float*)d_in[4];
    const float* rWk    = (const float*)d_in[5];
    const float* rbk    = (const float*)d_in[6];
    const float* wWk    = (const float*)d_in[7];
    const float* wbk    = (const float*)d_in[8];
    const float* wWe    = (const float*)d_in[9];
    const float* wbe    = (const float*)d_in[10];
    const float* wWa    = (const float*)d_in[11];
    const float* wba    = (const float*)d_in[12];

    float* out    = (float*)d_out;
    float* outmem = out + (size_t)NROW * 168;
    // xw scratch aliases the (dead until k_heads) mem-output region
    float* xw   = outmem;
    float* ctrl = (float*)d_ws;

    k_xw   <<<NROW/8, 512, 0, stream>>>(inputs, Wk, bias, xw);
    k_scan <<<BB,     512, 0, stream>>>(xw, Rk, ctrl);
    k_heads<<<NROW/4, 128, 0, stream>>>(ctrl, memory,
                                        rWk, rbk, wWk, wbk, wWe, wbe, wWa, wba,
                                        out, outmem);
}